// Round 8
// baseline (28048.050 us; speedup 1.0000x reference)
//
#include <hip/hip_runtime.h>
#include <math.h>

#define B_    512
#define T_    512
#define H_    256
#define DIN_  64
#define OL_   8
#define DOUT_ 64

typedef unsigned short u16;
typedef unsigned int u32;
typedef unsigned long long ull;
typedef __attribute__((ext_vector_type(8))) short short8;   // 8 bf16 (MFMA A/B frag)
typedef __attribute__((ext_vector_type(4))) float f32x4;    // MFMA C/D frag (16x16)

static __device__ __forceinline__ float sigm(float x){ return 1.0f/(1.0f + expf(-x)); }
static __device__ __forceinline__ float bf2f(u16 h){
  u32 u = ((u32)h) << 16; float f; __builtin_memcpy(&f, &u, 4); return f;
}
static __device__ __forceinline__ u16 f2bf(float f){        // RNE
  u32 u; __builtin_memcpy(&u, &f, 4);
  u = (u + 0x7fffu + ((u >> 16) & 1u)) >> 16;
  return (u16)u;
}
static __device__ __forceinline__ u32 packhl(float f){      // hi<<16 | lo
  u16 h = f2bf(f);
  u16 lo = f2bf(f - bf2f(h));
  return ((u32)h << 16) | (u32)lo;
}
static __device__ __forceinline__ float unpackhl(u32 w){
  return bf2f((u16)(w >> 16)) + bf2f((u16)(w & 0xffff));
}

// ---------------------------------------------------------------------------
// Weight preps
// ---------------------------------------------------------------------------
__global__ void k_wpt(const float* __restrict__ inW, const float* __restrict__ Wih,
                      float* __restrict__ WpT)
{
  int gid = blockIdx.x * 256 + threadIdx.x;   // 65536
  int c = gid >> 6, d = gid & 63;
  const float* wr = Wih + c * H_;
  const float* ir = inW + d * H_;
  float acc = 0.f;
  #pragma unroll 4
  for (int e = 0; e < H_; e += 4) {
    float4 av = *(const float4*)(ir + e);
    float4 bv = *(const float4*)(wr + e);
    acc += av.x*bv.x + av.y*bv.y + av.z*bv.z + av.w*bv.w;
  }
  WpT[c*64 + d] = acc;
}

__global__ void k_bp(const float* __restrict__ inb, const float* __restrict__ Wih,
                     const float* __restrict__ bih, const float* __restrict__ bhh,
                     float* __restrict__ bp)
{
  int c = blockIdx.x * 256 + threadIdx.x;   // 1024
  const float* wr = Wih + c * H_;
  float acc = bih[c] + bhh[c];
  for (int e = 0; e < H_; ++e) acc += inb[e] * wr[e];
  bp[c] = acc;
}

// dWt[k][j], j<768 covering dec gates i,g,o (f dead: c0=0)
__global__ void k_dwt(const float* __restrict__ dWih, float* __restrict__ dWt)
{
  int gid = blockIdx.x * 256 + threadIdx.x;   // 393216
  int j = gid >> 9, k = gid & 511;
  int row = (j < 256) ? j : (j + 256);
  dWt[k*768 + j] = dWih[row*512 + k];
}

// All 15 MLP weights W[k][n] -> fragment-linear bf16 hi/lo (one launch).
__global__ void k_wall(const float* __restrict__ wWs, const float* __restrict__ wWl,
                       const float* __restrict__ uWs, const float* __restrict__ uWl,
                       const float* __restrict__ vWs, u16* __restrict__ outb)
{
  int lyr = blockIdx.y;
  const float* W = (lyr < 3)  ? wWs + lyr*65536
                 : (lyr == 3) ? wWl
                 : (lyr < 7)  ? uWs + (lyr-4)*65536
                 : (lyr == 7) ? uWl
                 :              vWs + (lyr-8)*65536;
  u16* out = outb + (size_t)lyr*131072;
  int gid = blockIdx.x * 256 + threadIdx.x;   // 65536
  int k = gid & 255, n = gid >> 8;
  float v = W[k*256 + n];
  int s = k >> 5, j = k & 7;
  int lane = (((k >> 3) & 3) << 4) | (n & 15);
  int fl = ((s*16) + (n >> 4))*512 + lane*8 + j;
  u16 h = f2bf(v);
  out[fl] = h;
  out[65536 + fl] = f2bf(v - bf2f(h));
}

// Whh (1024x256) -> unit-group/gate fragment-linear: ctg = u16grp*4 + gate
__global__ void k_whhfl(const float* __restrict__ Whh, u16* __restrict__ out)
{
  int gid = blockIdx.x * 256 + threadIdx.x;   // 262144
  int j = gid & 7, l = (gid >> 3) & 63, ctg = (gid >> 9) & 63, s = gid >> 15;
  int k = s*32 + (l >> 4)*8 + j;
  int wv = ctg >> 2, g = ctg & 3;
  int row = g*256 + wv*16 + (l & 15);
  float v = Whh[row*256 + k];
  int fl = (s*64 + ctg)*512 + l*8 + j;
  u16 h = f2bf(v);
  out[fl] = h;
  out[262144 + fl] = f2bf(v - bf2f(h));
}

// WpT (1024x64) -> same layout (K=64)
__global__ void k_wpfl(const float* __restrict__ WpT, u16* __restrict__ out)
{
  int gid = blockIdx.x * 256 + threadIdx.x;   // 65536
  int j = gid & 7, l = (gid >> 3) & 63, ctg = (gid >> 9) & 63, s = gid >> 15;
  int k = s*32 + (l >> 4)*8 + j;              // < 64
  int wv = ctg >> 2, g = ctg & 3;
  int row = g*256 + wv*16 + (l & 15);
  float v = WpT[row*64 + k];
  int fl = (s*64 + ctg)*512 + l*8 + j;
  u16 h = f2bf(v);
  out[fl] = h;
  out[65536 + fl] = f2bf(v - bf2f(h));
}

// ---------------------------------------------------------------------------
// Clustered persistent encoder, sentinel flow-sync v2:
//  - each (t, rg) owns its own 128B sentinel line (stride 32 u32) -> no
//    cross-cluster line contention
//  - poll: lanes 0-7 of EVERY wave load the 8 flags (32 loads/block, one
//    parallel IC round trip), __all ballot -> each wave self-releases, no
//    extra barrier
//  - x loads issued before the poll; x-MFMAs before h-MFMAs (cover h-load RT)
// ---------------------------------------------------------------------------
__global__ __launch_bounds__(256,1) void k_enc(
    const float* __restrict__ x, const u16* __restrict__ whhFL,
    const u16* __restrict__ wpFL, const float* __restrict__ bp,
    u32* __restrict__ henc, u32* __restrict__ sent, int CB)
{
  __shared__ float G[16][32][4];   // [row][unit_local][gate], 8 KB
  const int tid = threadIdx.x, l = tid & 63, wv = tid >> 6;
  const int lr = l & 15, lk = l >> 4;
  const int rg = blockIdx.x, bg = blockIdx.y;
  const int ug2 = wv >> 1;                 // unit-16 half within block
  const int g0 = (wv & 1) * 2;             // this wave's gate pair
  const int u16g = bg*2 + ug2;             // global unit-16 group
  const int nrg = CB >> 4;

  // ---- resident weight fragments (~160 VGPR, no spill)
  short8 whH[8][2], whL[8][2], wpH[2][2], wpL[2][2];
  #pragma unroll
  for (int s = 0; s < 8; ++s)
    #pragma unroll
    for (int c = 0; c < 2; ++c) {
      int ctg = u16g*4 + g0 + c;
      whH[s][c] = *(const short8*)(whhFL + ((size_t)(s*64 + ctg))*512 + l*8);
      whL[s][c] = *(const short8*)(whhFL + 262144 + ((size_t)(s*64 + ctg))*512 + l*8);
    }
  #pragma unroll
  for (int s = 0; s < 2; ++s)
    #pragma unroll
    for (int c = 0; c < 2; ++c) {
      int ctg = u16g*4 + g0 + c;
      wpH[s][c] = *(const short8*)(wpFL + ((size_t)(s*64 + ctg))*512 + l*8);
      wpL[s][c] = *(const short8*)(wpFL + 65536 + ((size_t)(s*64 + ctg))*512 + l*8);
    }
  const int ul = tid & 31, er0 = tid >> 5;
  float bb[4];
  #pragma unroll
  for (int g = 0; g < 4; ++g) bb[g] = bp[g*256 + bg*32 + ul];
  float cs[2] = {0.f, 0.f};

  const size_t hstride = (size_t)CB * 256;
  const float* xrow = x + ((size_t)(rg*16 + lr)*T_)*DIN_ + lk*8;

  for (int t = 0; t < T_; ++t) {
    // ---- x(t) loads FIRST (HBM latency hides under the poll)
    float4 xv0 = *(const float4*)(xrow);
    float4 xv1 = *(const float4*)(xrow + 4);
    float4 xv2 = *(const float4*)(xrow + 32);
    float4 xv3 = *(const float4*)(xrow + 36);
    xrow += DIN_;

    // ---- poll step-(t-1) sentinels: lanes 0-7 per wave, ballot release
    if (t) {
      const u32* fp = sent + ((size_t)(t-1)*nrg + rg)*32;
      u32 f = 1u;
      if (l < 8) f = __hip_atomic_load(fp + l, __ATOMIC_RELAXED, __HIP_MEMORY_SCOPE_AGENT);
      while (!__all(f != 0u)) {
        __builtin_amdgcn_s_sleep(1);
        if (l < 8) f = __hip_atomic_load(fp + l, __ATOMIC_RELAXED, __HIP_MEMORY_SCOPE_AGENT);
      }
      __builtin_amdgcn_fence(__ATOMIC_ACQUIRE, "agent");
    }

    // ---- h(t-1) A-frags from IC (slot t)
    const ull* hb = (const ull*)(henc + (size_t)t*hstride + (size_t)(rg*16 + lr)*256);
    ull hq[8][4];
    #pragma unroll
    for (int s = 0; s < 8; ++s)
      #pragma unroll
      for (int q = 0; q < 4; ++q)
        hq[s][q] = __hip_atomic_load(hb + s*16 + lk*4 + q,
                                     __ATOMIC_RELAXED, __HIP_MEMORY_SCOPE_AGENT);

    f32x4 acc[2];
    acc[0] = (f32x4){0.f,0.f,0.f,0.f};
    acc[1] = (f32x4){0.f,0.f,0.f,0.f};

    // ---- x @ Wp' first (h loads still in flight)
    #pragma unroll
    for (int s = 0; s < 2; ++s) {
      float vv[8];
      if (s == 0) { vv[0]=xv0.x;vv[1]=xv0.y;vv[2]=xv0.z;vv[3]=xv0.w;vv[4]=xv1.x;vv[5]=xv1.y;vv[6]=xv1.z;vv[7]=xv1.w; }
      else        { vv[0]=xv2.x;vv[1]=xv2.y;vv[2]=xv2.z;vv[3]=xv2.w;vv[4]=xv3.x;vv[5]=xv3.y;vv[6]=xv3.z;vv[7]=xv3.w; }
      short8 ah, al;
      #pragma unroll
      for (int j = 0; j < 8; ++j) {
        u16 h = f2bf(vv[j]);
        ah[j] = (short)h;
        al[j] = (short)f2bf(vv[j] - bf2f(h));
      }
      #pragma unroll
      for (int c = 0; c < 2; ++c) {
        acc[c] = __builtin_amdgcn_mfma_f32_16x16x32_bf16(ah, wpH[s][c], acc[c], 0,0,0);
        acc[c] = __builtin_amdgcn_mfma_f32_16x16x32_bf16(al, wpH[s][c], acc[c], 0,0,0);
        acc[c] = __builtin_amdgcn_mfma_f32_16x16x32_bf16(ah, wpL[s][c], acc[c], 0,0,0);
      }
    }
    // ---- h @ Whh' (K = 256)
    #pragma unroll
    for (int s = 0; s < 8; ++s) {
      short8 ah, al;
      #pragma unroll
      for (int q = 0; q < 4; ++q) {
        u32 w0 = (u32)hq[s][q], w1 = (u32)(hq[s][q] >> 32);
        ah[q*2]   = (short)(w0 >> 16); al[q*2]   = (short)(w0 & 0xffff);
        ah[q*2+1] = (short)(w1 >> 16); al[q*2+1] = (short)(w1 & 0xffff);
      }
      #pragma unroll
      for (int c = 0; c < 2; ++c) {
        acc[c] = __builtin_amdgcn_mfma_f32_16x16x32_bf16(ah, whH[s][c], acc[c], 0,0,0);
        acc[c] = __builtin_amdgcn_mfma_f32_16x16x32_bf16(al, whH[s][c], acc[c], 0,0,0);
        acc[c] = __builtin_amdgcn_mfma_f32_16x16x32_bf16(ah, whL[s][c], acc[c], 0,0,0);
      }
    }

    // ---- gate exchange (C layout: col=lr -> unit u16g*16+lr, row=lk*4+j)
    #pragma unroll
    for (int c = 0; c < 2; ++c)
      #pragma unroll
      for (int j = 0; j < 4; ++j)
        G[lk*4 + j][ug2*16 + lr][g0 + c] = acc[c][j];
    __syncthreads();

    // ---- epilogue: 2 (row,unit) pairs per thread; c in regs; h -> IC
    #pragma unroll
    for (int p = 0; p < 2; ++p) {
      int row = er0 + p*8;
      float4 gq = *(const float4*)&G[row][ul][0];
      float gi = gq.x + bb[0], gf = gq.y + bb[1];
      float gg = gq.z + bb[2], go = gq.w + bb[3];
      float cn = sigm(gf)*cs[p] + sigm(gi)*tanhf(gg);
      float hn = sigm(go)*tanhf(cn);
      cs[p] = cn;
      __hip_atomic_store(henc + (size_t)(t+1)*hstride + (size_t)(rg*16 + row)*256 + bg*32 + ul,
                         packhl(hn), __ATOMIC_RELAXED, __HIP_MEMORY_SCOPE_AGENT);
    }
    __syncthreads();                 // drains all waves' h-stores
    if (t < T_ - 1 && tid == 0)
      __hip_atomic_store(sent + ((size_t)t*nrg + rg)*32 + bg, 1u,
                         __ATOMIC_RELEASE, __HIP_MEMORY_SCOPE_AGENT);
  }
}

// ---------------------------------------------------------------------------
// Fused multi-layer MLP, 64-row tile / 64KB LDS / 256 thr -> 2 blocks/CU.
// 4 waves = 4 col-groups; each wave covers all 64 rows x its 64 cols.
// IN: 0 = A0 fp32; 1 = tanh(A0 + us[m & cbm1]); 2 = A0 is packhl u32.
// FIN: 0 = fp32 C; 1 = dot with vWl -> e.
// ---------------------------------------------------------------------------
template<int IN, int FIN>
__global__ __launch_bounds__(256,2) void k_mlp(
    const float* __restrict__ A0, const float* __restrict__ usp,
    const u16* __restrict__ wFL, const float* __restrict__ bs,
    const float* __restrict__ bl, float* __restrict__ Cout,
    float* __restrict__ eout, const float* __restrict__ vWl,
    const float* __restrict__ vbl, int L, int nbs, int cbm1)
{
  extern __shared__ u32 act[];   // [64][256] u32, chunk-swizzled (key row&7)
  const int tid = threadIdx.x, l = tid & 63, cg = tid >> 6;
  const int lr = l & 15, lk = l >> 4;
  const long m0 = (long)blockIdx.x * 64;

  for (int i = tid; i < 4096; i += 256) {        // 64 rows x 64 chunks
    int row = i >> 6, c16 = i & 63;
    long m = m0 + row;
    uint4 pk;
    if (IN == 2) {
      pk = *(const uint4*)((const u32*)A0 + m*256 + c16*4);
    } else {
      float4 v = *(const float4*)(A0 + m*256 + c16*4);
      if (IN == 1) {
        const float* ub = usp + (size_t)(m & cbm1)*256;
        float4 u4 = *(const float4*)(ub + c16*4);
        v.x = tanhf(v.x + u4.x); v.y = tanhf(v.y + u4.y);
        v.z = tanhf(v.z + u4.z); v.w = tanhf(v.w + u4.w);
      }
      pk = (uint4){packhl(v.x), packhl(v.y), packhl(v.z), packhl(v.w)};
    }
    *((uint4*)(act + row*256 + ((c16 ^ (row & 7)) << 2))) = pk;
  }

  f32x4 acc[4][4];
  for (int lyr = 0; lyr < L; ++lyr) {
    __syncthreads();
    const u16* wb = wFL + (size_t)lyr*131072;
    #pragma unroll
    for (int rt = 0; rt < 4; ++rt)
      #pragma unroll
      for (int ct = 0; ct < 4; ++ct) acc[rt][ct] = (f32x4){0.f,0.f,0.f,0.f};

    short8 bh[2][4], blo[2][4];
    #pragma unroll
    for (int ct = 0; ct < 4; ++ct) {
      const u16* bfp = wb + ((size_t)(cg*4 + ct))*512 + l*8;
      bh[0][ct]  = *(const short8*)bfp;
      blo[0][ct] = *(const short8*)(bfp + 65536);
    }
    #pragma unroll
    for (int s = 0; s < 8; ++s) {
      const int pb = s & 1, nb = pb ^ 1;
      if (s < 7) {
        #pragma unroll
        for (int ct = 0; ct < 4; ++ct) {
          const u16* bfp = wb + ((size_t)((s+1)*16 + cg*4 + ct))*512 + l*8;
          bh[nb][ct]  = *(const short8*)bfp;
          blo[nb][ct] = *(const short8*)(bfp + 65536);
        }
      }
      short8 ah[4], al[4];
      #pragma unroll
      for (int rt = 0; rt < 4; ++rt) {
        int row = rt*16 + lr;
        int cc = s*8 + lk*2;
        const u32* base = act + row*256;
        uint4 d0 = *(const uint4*)(base + (((cc    ) ^ (row & 7)) << 2));
        uint4 d1 = *(const uint4*)(base + (((cc + 1) ^ (row & 7)) << 2));
        u32 q[8] = {d0.x,d0.y,d0.z,d0.w,d1.x,d1.y,d1.z,d1.w};
        #pragma unroll
        for (int j = 0; j < 8; ++j) {
          ah[rt][j] = (short)(q[j] >> 16);
          al[rt][j] = (short)(q[j] & 0xffff);
        }
      }
      #pragma unroll
      for (int ct = 0; ct < 4; ++ct)
        #pragma unroll
        for (int rt = 0; rt < 4; ++rt) {
          acc[rt][ct] = __builtin_amdgcn_mfma_f32_16x16x32_bf16(ah[rt], bh[pb][ct],  acc[rt][ct], 0,0,0);
          acc[rt][ct] = __builtin_amdgcn_mfma_f32_16x16x32_bf16(al[rt], bh[pb][ct],  acc[rt][ct], 0,0,0);
          acc[rt][ct] = __builtin_amdgcn_mfma_f32_16x16x32_bf16(ah[rt], blo[pb][ct], acc[rt][ct], 0,0,0);
        }
    }
    const float* bptr = (lyr < nbs) ? (bs + lyr*256) : bl;
    const bool dorelu = (lyr < L-1) || (FIN == 1);
    #pragma unroll
    for (int ct = 0; ct < 4; ++ct) {
      float bv = bptr[cg*64 + ct*16 + lr];
      #pragma unroll
      for (int rt = 0; rt < 4; ++rt)
        #pragma unroll
        for (int g = 0; g < 4; ++g) {
          float xv = acc[rt][ct][g] + bv;
          acc[rt][ct][g] = dorelu ? fmaxf(xv, 0.f) : xv;
        }
    }
    if (lyr == L-1) break;
    __syncthreads();
    #pragma unroll
    for (int ct = 0; ct < 4; ++ct) {
      int n = cg*64 + ct*16 + lr;
      #pragma unroll
      for (int rt = 0; rt < 4; ++rt)
        #pragma unroll
        for (int g = 0; g < 4; ++g) {
          int row = rt*16 + lk*4 + g;
          act[row*256 + (((n >> 2) ^ (row & 7)) << 2) + (n & 3)] = packhl(acc[rt][ct][g]);
        }
    }
  }

  if (FIN == 0) {
    #pragma unroll
    for (int ct = 0; ct < 4; ++ct) {
      int n = cg*64 + ct*16 + lr;
      #pragma unroll
      for (int rt = 0; rt < 4; ++rt)
        #pragma unroll
        for (int g = 0; g < 4; ++g) {
          long m = m0 + rt*16 + lk*4 + g;
          Cout[m*256 + n] = acc[rt][ct][g];
        }
    }
  } else {
    float part[4][4];
    #pragma unroll
    for (int rt = 0; rt < 4; ++rt)
      #pragma unroll
      for (int g = 0; g < 4; ++g) part[rt][g] = 0.f;
    #pragma unroll
    for (int ct = 0; ct < 4; ++ct) {
      float vw = vWl[cg*64 + ct*16 + lr];
      #pragma unroll
      for (int rt = 0; rt < 4; ++rt)
        #pragma unroll
        for (int g = 0; g < 4; ++g) part[rt][g] += acc[rt][ct][g] * vw;
    }
    #pragma unroll
    for (int o = 1; o < 16; o <<= 1)
      #pragma unroll
      for (int rt = 0; rt < 4; ++rt)
        #pragma unroll
        for (int g = 0; g < 4; ++g) part[rt][g] += __shfl_xor(part[rt][g], o, 64);
    __syncthreads();
    float* ep = (float*)act;                      // [4][64]
    if ((l & 15) == 0) {
      #pragma unroll
      for (int rt = 0; rt < 4; ++rt)
        #pragma unroll
        for (int g = 0; g < 4; ++g)
          ep[cg*64 + rt*16 + lk*4 + g] = part[rt][g];
    }
    __syncthreads();
    if (tid < 64)
      eout[m0 + tid] = ep[tid] + ep[64 + tid] + ep[128 + tid] + ep[192 + tid] + vbl[0];
  }
}

// ---------------------------------------------------------------------------
// Fused softmax + context over henc (t-major, packed hi/lo). e[t*CB + b].
// ---------------------------------------------------------------------------
__global__ __launch_bounds__(256,2) void k_attn(const float* __restrict__ e,
    const u32* __restrict__ henc, float* __restrict__ ct, int CB)
{
  __shared__ float as[512];
  __shared__ float red[8];
  const int b = blockIdx.x, tid = threadIdx.x;
  const int lane = tid & 63, w = tid >> 6;
  float v0 = e[(size_t)tid*CB + b];
  float v1 = e[(size_t)(tid + 256)*CB + b];
  float m = fmaxf(v0, v1);
  #pragma unroll
  for (int o = 32; o; o >>= 1) m = fmaxf(m, __shfl_xor(m, o, 64));
  if (!lane) red[w] = m;
  __syncthreads();
  m = fmaxf(fmaxf(red[0], red[1]), fmaxf(red[2], red[3]));
  float x0 = expf(v0 - m), x1 = expf(v1 - m);
  float sm = x0 + x1;
  #pragma unroll
  for (int o = 32; o; o >>= 1) sm += __shfl_xor(sm, o, 64);
  if (!lane) red[4 + w] = sm;
  __syncthreads();
  float inv = 1.f / (red[4] + red[5] + red[6] + red[7]);
  as[tid] = x0 * inv;
  as[256 + tid] = x1 * inv;
  __syncthreads();
  float acc = 0.f;
  const u32* ep = henc + (size_t)(CB + b)*256 + tid;   // slot 1, unit=tid
  const size_t ts = (size_t)CB * 256;
  #pragma unroll 8
  for (int t = 0; t < 512; ++t) acc += as[t] * unpackhl(ep[t*ts]);
  ct[b*H_ + tid] = acc;
}

__global__ __launch_bounds__(256,2) void k_dec_cell(
    const float* __restrict__ ct, float* __restrict__ s, const float* __restrict__ dWt,
    const float* __restrict__ bih, const float* __restrict__ bhh,
    float* __restrict__ dec, int step)
{
  __shared__ float xt[4][516];
  const int tid = threadIdx.x;
  const int b0 = blockIdx.x * 4;
  for (int f = tid; f < 4*128; f += 256) {
    int bb = f >> 7, k4 = f & 127;
    float4 v = (k4 < 64) ? *(const float4*)(ct + (b0+bb)*H_ + k4*4)
                         : *(const float4*)(s  + (b0+bb)*H_ + (k4-64)*4);
    *(float4*)(&xt[bb][k4*4]) = v;
  }
  __syncthreads();
  const int u = tid;
  float ai[4], ag[4], ao[4];
  #pragma unroll
  for (int bb = 0; bb < 4; ++bb) { ai[bb]=0.f; ag[bb]=0.f; ao[bb]=0.f; }
  #pragma unroll 4
  for (int k = 0; k < 512; ++k) {
    float wi = dWt[k*768 + u];
    float wg = dWt[k*768 + 256 + u];
    float wo = dWt[k*768 + 512 + u];
    #pragma unroll
    for (int bb = 0; bb < 4; ++bb) {
      float xv = xt[bb][k];
      ai[bb] += xv*wi; ag[bb] += xv*wg; ao[bb] += xv*wo;
    }
  }
  float bi = bih[u]       + bhh[u];
  float bg = bih[512 + u] + bhh[512 + u];
  float bo = bih[768 + u] + bhh[768 + u];
  #pragma unroll
  for (int bb = 0; bb < 4; ++bb) {
    int b = b0 + bb;
    float cn = sigm(ai[bb] + bi) * tanhf(ag[bb] + bg);
    float hn = sigm(ao[bb] + bo) * tanhf(cn);
    s[b*H_ + u] = hn;
    dec[((size_t)b*OL_ + step)*H_ + u] = hn;
  }
}

__global__ __launch_bounds__(256,2) void k_outproj(
    const float* __restrict__ dec, const float* __restrict__ oW,
    const float* __restrict__ ob, float* __restrict__ out)
{
  const int tid = threadIdx.x;
  const int m0 = blockIdx.x * 16;
  const int d = tid & 63, rr = tid >> 6;
  float bv = ob[d];
  for (int p = 0; p < 4; ++p) {
    int m = m0 + p*4 + rr;
    const float* ar = dec + (size_t)m*H_;
    float acc = bv;
    #pragma unroll 4
    for (int k = 0; k < H_; ++k) acc += ar[k] * oW[k*64 + d];
    out[(size_t)m*64 + d] = acc;
  }
}

// ---------------------------------------------------------------------------
extern "C" void kernel_launch(void* const* d_in, const int* in_sizes, int n_in,
                              void* d_out, int out_size, void* d_ws, size_t ws_size,
                              hipStream_t stream)
{
  (void)in_sizes; (void)n_in;
  const float* x    = (const float*)d_in[0];
  const float* inW  = (const float*)d_in[1];
  const float* inb  = (const float*)d_in[2];
  const float* eWih = (const float*)d_in[3];
  const float* eWhh = (const float*)d_in[4];
  const float* ebih = (const float*)d_in[5];
  const float* ebhh = (const float*)d_in[6];
  const float* dWih = (const float*)d_in[7];
  const float* dbih = (const float*)d_in[9];
  const float* dbhh = (const float*)d_in[10];
  const float* wWs  = (const float*)d_in[11];
  const float* wbs  = (const float*)d_in[12];
  const float* wWl  = (const float*)d_in[13];
  const float* wbl  = (const float*)d_in[14];
  const float* uWs  = (const float*)d_in[15];
  const float* ubs  = (const float*)d_in[16];
  const float* uWl  = (const float*)d_in[17];
  const float* ubl  = (const float*)d_in[18];
  const float* vWs  = (const float*)d_in[19];
  const float* vbs  = (const float*)d_in[20];
  const float* vWl  = (const float*)d_in[21];
  const float* vbl  = (const float*)d_in[22];
  const float* oW   = (const float*)d_in[23];
  const float* ob   = (const float*)d_in[24];
  float* out = (float*)d_out;

  hipFuncSetAttribute((const void*)k_mlp<0,0>, hipFuncAttributeMaxDynamicSharedMemorySize, 65536);
  hipFuncSetAttribute((const void*)k_mlp<1,1>, hipFuncAttributeMaxDynamicSharedMemorySize, 65536);
  hipFuncSetAttribute((const void*)k_mlp<2,0>, hipFuncAttributeMaxDynamicSharedMemorySize, 65536);

  const size_t avail = ws_size / 4;
  auto need = [](int cb) -> size_t {
    return (size_t)(T_+1)*cb*256        // henc (u32)
         + (size_t)cb*T_*256            // whs
         + (size_t)cb*1024              // sentinels (u32), line-padded
         + (size_t)cb*3328              // sbuf,us,ctx,dec,e
         + 1300000ull;                  // preps + pad
  };
  int CB = 512;
  while (CB > 128 && need(CB) > avail) CB >>= 1;
  if (need(CB) > avail) { hipMemsetAsync(d_out, 0, (size_t)out_size*4, stream); return; }

  float* wsf = (float*)d_ws;
  size_t o = 0;
  u32* henc = (u32*)(wsf + o);  o += (size_t)(T_+1)*CB*256;
  float* whs = wsf + o;  o += (size_t)CB*T_*256;
  u32* sent = (u32*)(wsf + o);  o += (size_t)CB*1024;
  float* sbuf= wsf + o;  o += (size_t)CB*256;
  float* us  = wsf + o;  o += (size_t)CB*256;
  float* ctx = wsf + o;  o += (size_t)CB*256;
  float* dec = wsf + o;  o += (size_t)CB*2048;
  float* e   = wsf + o;  o += (size_t)CB*512;
  float* WpT = wsf + o;  o += 65536;
  float* bp  = wsf + o;  o += 1024;
  float* dWt = wsf + o;  o += 393216;
  u16* whhFL = (u16*)(wsf + o);  o += 262144;
  u16* wpFL  = (u16*)(wsf + o);  o += 65536;
  u16* mlpFL = (u16*)(wsf + o);

  // ---- weight preps (chunk-invariant)
  k_wpt<<<256, 256, 0, stream>>>(inW, eWih, WpT);
  k_bp <<<4,   256, 0, stream>>>(inb, eWih, ebih, ebhh, bp);
  k_dwt<<<1536,256, 0, stream>>>(dWih, dWt);
  k_whhfl<<<1024,256,0,stream>>>(eWhh, whhFL);
  k_wpfl <<<256, 256,0,stream>>>(WpT, wpFL);
  k_wall <<<dim3(256,15), 256, 0, stream>>>(wWs, wWl, uWs, uWl, vWs, mlpFL);

  const int gBig = CB * 8;            // (CB*T)/64 row-tiles
  const int gU   = CB / 64;
  const int cbm1 = CB - 1;

  for (int c0 = 0; c0 < B_; c0 += CB) {
    const float* xc = x + (size_t)c0*T_*DIN_;
    float* outc = out + (size_t)c0*OL_*DOUT_;

    hipMemsetAsync(henc, 0, (size_t)CB*1024, stream);     // slot 0 = h(-1) = 0
    hipMemsetAsync(sent, 0, (size_t)CB*4096, stream);     // sentinels
    hipMemsetAsync(sbuf, 0, (size_t)CB*1024, stream);     // decode s0 = 0

    // ---- clustered persistent encoder (sentinel flow-sync v2)
    k_enc<<<dim3(CB/16, 8), 256, 0, stream>>>(xc, whhFL, wpFL, bp, henc, sent, CB);

    // ---- whs = w_mlp(enc)   rows m' = t*CB + b  (= henc slots 1..512 linear)
    k_mlp<2,0><<<gBig, 256, 65536, stream>>>((const float*)(henc + (size_t)CB*256),
                                             nullptr, mlpFL, wbs, wbl,
                                             whs, nullptr, nullptr, nullptr, 4, 3, 0);

    // ---- decode loop
    for (int step = 0; step < OL_; ++step) {
      k_mlp<0,0><<<gU, 256, 65536, stream>>>(sbuf, nullptr, mlpFL + 4ull*131072, ubs, ubl,
                                             us, nullptr, nullptr, nullptr, 4, 3, 0);
      k_mlp<1,1><<<gBig, 256, 65536, stream>>>(whs, us, mlpFL + 8ull*131072, vbs, nullptr,
                                               nullptr, e, vWl, vbl, 7, 7, cbm1);
      k_attn<<<CB, 256, 0, stream>>>(e, henc, ctx, CB);
      k_dec_cell<<<CB/4, 256, 0, stream>>>(ctx, sbuf, dWt, dbih, dbhh, dec, step);
    }
    k_outproj<<<CB/2, 256, 0, stream>>>(dec, oW, ob, outc);
  }
}

// Round 9
// 19199.559 us; speedup vs baseline: 1.4609x; 1.4609x over previous
//
#include <hip/hip_runtime.h>
#include <math.h>

#define B_    512
#define T_    512
#define H_    256
#define DIN_  64
#define OL_   8
#define DOUT_ 64

typedef unsigned short u16;
typedef unsigned int u32;
typedef unsigned long long ull;
typedef __attribute__((ext_vector_type(8))) short short8;   // 8 bf16 (MFMA A/B frag)
typedef __attribute__((ext_vector_type(4))) float f32x4;    // MFMA C/D frag (16x16)

static __device__ __forceinline__ float sigm(float x){ return 1.0f/(1.0f + expf(-x)); }
static __device__ __forceinline__ float bf2f(u16 h){
  u32 u = ((u32)h) << 16; float f; __builtin_memcpy(&f, &u, 4); return f;
}
static __device__ __forceinline__ u16 f2bf(float f){        // RNE
  u32 u; __builtin_memcpy(&u, &f, 4);
  u = (u + 0x7fffu + ((u >> 16) & 1u)) >> 16;
  return (u16)u;
}
static __device__ __forceinline__ u32 packhl(float f){      // hi<<16 | lo
  u16 h = f2bf(f);
  u16 lo = f2bf(f - bf2f(h));
  return ((u32)h << 16) | (u32)lo;
}
static __device__ __forceinline__ float unpackhl(u32 w){
  return bf2f((u16)(w >> 16)) + bf2f((u16)(w & 0xffff));
}

// ---------------------------------------------------------------------------
// Weight preps
// ---------------------------------------------------------------------------
__global__ void k_wpt(const float* __restrict__ inW, const float* __restrict__ Wih,
                      float* __restrict__ WpT)
{
  int gid = blockIdx.x * 256 + threadIdx.x;   // 65536
  int c = gid >> 6, d = gid & 63;
  const float* wr = Wih + c * H_;
  const float* ir = inW + d * H_;
  float acc = 0.f;
  #pragma unroll 4
  for (int e = 0; e < H_; e += 4) {
    float4 av = *(const float4*)(ir + e);
    float4 bv = *(const float4*)(wr + e);
    acc += av.x*bv.x + av.y*bv.y + av.z*bv.z + av.w*bv.w;
  }
  WpT[c*64 + d] = acc;
}

__global__ void k_bp(const float* __restrict__ inb, const float* __restrict__ Wih,
                     const float* __restrict__ bih, const float* __restrict__ bhh,
                     float* __restrict__ bp)
{
  int c = blockIdx.x * 256 + threadIdx.x;   // 1024
  const float* wr = Wih + c * H_;
  float acc = bih[c] + bhh[c];
  for (int e = 0; e < H_; ++e) acc += inb[e] * wr[e];
  bp[c] = acc;
}

// dWt[k][j], j<768 covering dec gates i,g,o (f dead: c0=0)
__global__ void k_dwt(const float* __restrict__ dWih, float* __restrict__ dWt)
{
  int gid = blockIdx.x * 256 + threadIdx.x;   // 393216
  int j = gid >> 9, k = gid & 511;
  int row = (j < 256) ? j : (j + 256);
  dWt[k*768 + j] = dWih[row*512 + k];
}

// All 15 MLP weights W[k][n] -> fragment-linear bf16 hi/lo (one launch).
__global__ void k_wall(const float* __restrict__ wWs, const float* __restrict__ wWl,
                       const float* __restrict__ uWs, const float* __restrict__ uWl,
                       const float* __restrict__ vWs, u16* __restrict__ outb)
{
  int lyr = blockIdx.y;
  const float* W = (lyr < 3)  ? wWs + lyr*65536
                 : (lyr == 3) ? wWl
                 : (lyr < 7)  ? uWs + (lyr-4)*65536
                 : (lyr == 7) ? uWl
                 :              vWs + (lyr-8)*65536;
  u16* out = outb + (size_t)lyr*131072;
  int gid = blockIdx.x * 256 + threadIdx.x;   // 65536
  int k = gid & 255, n = gid >> 8;
  float v = W[k*256 + n];
  int s = k >> 5, j = k & 7;
  int lane = (((k >> 3) & 3) << 4) | (n & 15);
  int fl = ((s*16) + (n >> 4))*512 + lane*8 + j;
  u16 h = f2bf(v);
  out[fl] = h;
  out[65536 + fl] = f2bf(v - bf2f(h));
}

// Whh (1024x256) -> unit-group/gate fragment-linear: ctg = u16grp*4 + gate
__global__ void k_whhfl(const float* __restrict__ Whh, u16* __restrict__ out)
{
  int gid = blockIdx.x * 256 + threadIdx.x;   // 262144
  int j = gid & 7, l = (gid >> 3) & 63, ctg = (gid >> 9) & 63, s = gid >> 15;
  int k = s*32 + (l >> 4)*8 + j;
  int wv = ctg >> 2, g = ctg & 3;
  int row = g*256 + wv*16 + (l & 15);
  float v = Whh[row*256 + k];
  int fl = (s*64 + ctg)*512 + l*8 + j;
  u16 h = f2bf(v);
  out[fl] = h;
  out[262144 + fl] = f2bf(v - bf2f(h));
}

// WpT (1024x64) -> same layout (K=64)
__global__ void k_wpfl(const float* __restrict__ WpT, u16* __restrict__ out)
{
  int gid = blockIdx.x * 256 + threadIdx.x;   // 65536
  int j = gid & 7, l = (gid >> 3) & 63, ctg = (gid >> 9) & 63, s = gid >> 15;
  int k = s*32 + (l >> 4)*8 + j;              // < 64
  int wv = ctg >> 2, g = ctg & 3;
  int row = g*256 + wv*16 + (l & 15);
  float v = WpT[row*64 + k];
  int fl = (s*64 + ctg)*512 + l*8 + j;
  u16 h = f2bf(v);
  out[fl] = h;
  out[65536 + fl] = f2bf(v - bf2f(h));
}

// ---------------------------------------------------------------------------
// Clustered persistent encoder, DATA-AS-FLAG sync:
// h stored as packhl(h)|1 into henc slot t+1 (never overwritten, pre-zeroed).
// Consumers poll the h-words themselves until all nonzero (4B atomic loads are
// untearable; value-carried dep -> no fences, no sentinels, no store-drain
// barrier). G exchange ping-pongs -> exactly ONE __syncthreads per step.
// grid = (CB/16, 8, NC): NC chunks' encoders run concurrently (independent).
// All blocks co-resident (<=128 blocks on 256 CUs) -> deadlock-free.
// ---------------------------------------------------------------------------
__global__ __launch_bounds__(256,1) void k_enc(
    const float* __restrict__ x, const u16* __restrict__ whhFL,
    const u16* __restrict__ wpFL, const float* __restrict__ bp,
    u32* __restrict__ henc, int CB)
{
  __shared__ float G[2][16][32][4];   // ping-pong gate exchange, 16 KB
  const int tid = threadIdx.x, l = tid & 63, wv = tid >> 6;
  const int lr = l & 15, lk = l >> 4;
  const int rg = blockIdx.x, bg = blockIdx.y, z = blockIdx.z;
  const int ug2 = wv >> 1;                 // unit-16 half within block
  const int g0 = (wv & 1) * 2;             // this wave's gate pair
  const int u16g = bg*2 + ug2;             // global unit-16 group

  // ---- resident weight fragments (~160 VGPR, no spill)
  short8 whH[8][2], whL[8][2], wpH[2][2], wpL[2][2];
  #pragma unroll
  for (int s = 0; s < 8; ++s)
    #pragma unroll
    for (int c = 0; c < 2; ++c) {
      int ctg = u16g*4 + g0 + c;
      whH[s][c] = *(const short8*)(whhFL + ((size_t)(s*64 + ctg))*512 + l*8);
      whL[s][c] = *(const short8*)(whhFL + 262144 + ((size_t)(s*64 + ctg))*512 + l*8);
    }
  #pragma unroll
  for (int s = 0; s < 2; ++s)
    #pragma unroll
    for (int c = 0; c < 2; ++c) {
      int ctg = u16g*4 + g0 + c;
      wpH[s][c] = *(const short8*)(wpFL + ((size_t)(s*64 + ctg))*512 + l*8);
      wpL[s][c] = *(const short8*)(wpFL + 65536 + ((size_t)(s*64 + ctg))*512 + l*8);
    }
  const int ul = tid & 31, er0 = tid >> 5;
  float bb[4];
  #pragma unroll
  for (int g = 0; g < 4; ++g) bb[g] = bp[g*256 + bg*32 + ul];
  float cs[2] = {0.f, 0.f};

  const size_t hstride = (size_t)CB * 256;
  u32* hz = henc + (size_t)z * (size_t)(T_+1) * hstride;
  const float* xrow = x + ((size_t)(z*CB + rg*16 + lr)*T_)*DIN_ + lk*8;

  for (int t = 0; t < T_; ++t) {
    // ---- x(t) loads first
    float4 xv0 = *(const float4*)(xrow);
    float4 xv1 = *(const float4*)(xrow + 4);
    float4 xv2 = *(const float4*)(xrow + 32);
    float4 xv3 = *(const float4*)(xrow + 36);
    xrow += DIN_;

    // ---- h(t-1) from IC slot t; the data is its own readiness flag
    const ull* hb = (const ull*)(hz + (size_t)t*hstride + (size_t)(rg*16 + lr)*256);
    ull hq[8][4];
    #pragma unroll
    for (int s = 0; s < 8; ++s)
      #pragma unroll
      for (int q = 0; q < 4; ++q)
        hq[s][q] = __hip_atomic_load(hb + s*16 + lk*4 + q,
                                     __ATOMIC_RELAXED, __HIP_MEMORY_SCOPE_AGENT);
    if (t) {
      for (;;) {
        bool ok = true;
        #pragma unroll
        for (int s = 0; s < 8; ++s)
          #pragma unroll
          for (int q = 0; q < 4; ++q) {
            u32 a = (u32)hq[s][q], b = (u32)(hq[s][q] >> 32);
            ok = ok && (a != 0u) && (b != 0u);
          }
        if (__all(ok)) break;
        __builtin_amdgcn_s_sleep(1);
        #pragma unroll
        for (int s = 0; s < 8; ++s)
          #pragma unroll
          for (int q = 0; q < 4; ++q)
            hq[s][q] = __hip_atomic_load(hb + s*16 + lk*4 + q,
                                         __ATOMIC_RELAXED, __HIP_MEMORY_SCOPE_AGENT);
      }
    }

    f32x4 acc[2];
    acc[0] = (f32x4){0.f,0.f,0.f,0.f};
    acc[1] = (f32x4){0.f,0.f,0.f,0.f};

    // ---- x @ Wp'
    #pragma unroll
    for (int s = 0; s < 2; ++s) {
      float vv[8];
      if (s == 0) { vv[0]=xv0.x;vv[1]=xv0.y;vv[2]=xv0.z;vv[3]=xv0.w;vv[4]=xv1.x;vv[5]=xv1.y;vv[6]=xv1.z;vv[7]=xv1.w; }
      else        { vv[0]=xv2.x;vv[1]=xv2.y;vv[2]=xv2.z;vv[3]=xv2.w;vv[4]=xv3.x;vv[5]=xv3.y;vv[6]=xv3.z;vv[7]=xv3.w; }
      short8 ah, al;
      #pragma unroll
      for (int j = 0; j < 8; ++j) {
        u16 h = f2bf(vv[j]);
        ah[j] = (short)h;
        al[j] = (short)f2bf(vv[j] - bf2f(h));
      }
      #pragma unroll
      for (int c = 0; c < 2; ++c) {
        acc[c] = __builtin_amdgcn_mfma_f32_16x16x32_bf16(ah, wpH[s][c], acc[c], 0,0,0);
        acc[c] = __builtin_amdgcn_mfma_f32_16x16x32_bf16(al, wpH[s][c], acc[c], 0,0,0);
        acc[c] = __builtin_amdgcn_mfma_f32_16x16x32_bf16(ah, wpL[s][c], acc[c], 0,0,0);
      }
    }
    // ---- h @ Whh' (K = 256)
    #pragma unroll
    for (int s = 0; s < 8; ++s) {
      short8 ah, al;
      #pragma unroll
      for (int q = 0; q < 4; ++q) {
        u32 w0 = (u32)hq[s][q], w1 = (u32)(hq[s][q] >> 32);
        ah[q*2]   = (short)(w0 >> 16); al[q*2]   = (short)(w0 & 0xffff);
        ah[q*2+1] = (short)(w1 >> 16); al[q*2+1] = (short)(w1 & 0xffff);
      }
      #pragma unroll
      for (int c = 0; c < 2; ++c) {
        acc[c] = __builtin_amdgcn_mfma_f32_16x16x32_bf16(ah, whH[s][c], acc[c], 0,0,0);
        acc[c] = __builtin_amdgcn_mfma_f32_16x16x32_bf16(al, whH[s][c], acc[c], 0,0,0);
        acc[c] = __builtin_amdgcn_mfma_f32_16x16x32_bf16(ah, whL[s][c], acc[c], 0,0,0);
      }
    }

    // ---- gate exchange via ping-pong G (one barrier per step)
    const int p = t & 1;
    #pragma unroll
    for (int c = 0; c < 2; ++c)
      #pragma unroll
      for (int j = 0; j < 4; ++j)
        G[p][lk*4 + j][ug2*16 + lr][g0 + c] = acc[c][j];
    __syncthreads();

    // ---- epilogue: c/h update; h -> IC with LSB marker (data-as-flag)
    #pragma unroll
    for (int pp = 0; pp < 2; ++pp) {
      int row = er0 + pp*8;
      float4 gq = *(const float4*)&G[p][row][ul][0];
      float gi = gq.x + bb[0], gf = gq.y + bb[1];
      float gg = gq.z + bb[2], go = gq.w + bb[3];
      float cn = sigm(gf)*cs[pp] + sigm(gi)*tanhf(gg);
      float hn = sigm(go)*tanhf(cn);
      cs[pp] = cn;
      __hip_atomic_store(hz + (size_t)(t+1)*hstride + (size_t)(rg*16 + row)*256 + bg*32 + ul,
                         packhl(hn) | 1u, __ATOMIC_RELAXED, __HIP_MEMORY_SCOPE_AGENT);
    }
    // no tail barrier: next step writes G[p^1]; consumers poll the data itself
  }
}

// ---------------------------------------------------------------------------
// Fused multi-layer MLP, 64-row tile / 64KB LDS / 256 thr.
// IN: 0 = A0 fp32; 2 = A0 packhl u32 (copy);
//     3 = A0 packhl u32, x = tanh(unpack + us[m & cbm1]).
// FIN: 0 = write C (fp32 or packed per OUTP); 1 = dot with vWl -> e.
// OUTP: 1 = write C as packhl u32.
// ---------------------------------------------------------------------------
template<int IN, int FIN, int OUTP>
__global__ __launch_bounds__(256,2) void k_mlp(
    const float* __restrict__ A0, const float* __restrict__ usp,
    const u16* __restrict__ wFL, const float* __restrict__ bs,
    const float* __restrict__ bl, float* __restrict__ Cout,
    float* __restrict__ eout, const float* __restrict__ vWl,
    const float* __restrict__ vbl, int L, int nbs, int cbm1)
{
  extern __shared__ u32 act[];   // [64][256] u32, chunk-swizzled (key row&7)
  const int tid = threadIdx.x, l = tid & 63, cg = tid >> 6;
  const int lr = l & 15, lk = l >> 4;
  const long m0 = (long)blockIdx.x * 64;

  for (int i = tid; i < 4096; i += 256) {        // 64 rows x 64 chunks
    int row = i >> 6, c16 = i & 63;
    long m = m0 + row;
    uint4 pk;
    if (IN == 2) {
      pk = *(const uint4*)((const u32*)A0 + m*256 + c16*4);
    } else {
      float4 v;
      if (IN == 3) {
        uint4 pw = *(const uint4*)((const u32*)A0 + m*256 + c16*4);
        v.x = unpackhl(pw.x); v.y = unpackhl(pw.y);
        v.z = unpackhl(pw.z); v.w = unpackhl(pw.w);
      } else {
        v = *(const float4*)(A0 + m*256 + c16*4);
      }
      if (IN == 1 || IN == 3) {
        const float* ub = usp + (size_t)(m & cbm1)*256;
        float4 u4 = *(const float4*)(ub + c16*4);
        v.x = tanhf(v.x + u4.x); v.y = tanhf(v.y + u4.y);
        v.z = tanhf(v.z + u4.z); v.w = tanhf(v.w + u4.w);
      }
      pk = (uint4){packhl(v.x), packhl(v.y), packhl(v.z), packhl(v.w)};
    }
    *((uint4*)(act + row*256 + ((c16 ^ (row & 7)) << 2))) = pk;
  }

  f32x4 acc[4][4];
  for (int lyr = 0; lyr < L; ++lyr) {
    __syncthreads();
    const u16* wb = wFL + (size_t)lyr*131072;
    #pragma unroll
    for (int rt = 0; rt < 4; ++rt)
      #pragma unroll
      for (int ct = 0; ct < 4; ++ct) acc[rt][ct] = (f32x4){0.f,0.f,0.f,0.f};

    short8 bh[2][4], blo[2][4];
    #pragma unroll
    for (int ct = 0; ct < 4; ++ct) {
      const u16* bfp = wb + ((size_t)(cg*4 + ct))*512 + l*8;
      bh[0][ct]  = *(const short8*)bfp;
      blo[0][ct] = *(const short8*)(bfp + 65536);
    }
    #pragma unroll
    for (int s = 0; s < 8; ++s) {
      const int pb = s & 1, nb = pb ^ 1;
      if (s < 7) {
        #pragma unroll
        for (int ct = 0; ct < 4; ++ct) {
          const u16* bfp = wb + ((size_t)((s+1)*16 + cg*4 + ct))*512 + l*8;
          bh[nb][ct]  = *(const short8*)bfp;
          blo[nb][ct] = *(const short8*)(bfp + 65536);
        }
      }
      short8 ah[4], al[4];
      #pragma unroll
      for (int rt = 0; rt < 4; ++rt) {
        int row = rt*16 + lr;
        int cc = s*8 + lk*2;
        const u32* base = act + row*256;
        uint4 d0 = *(const uint4*)(base + (((cc    ) ^ (row & 7)) << 2));
        uint4 d1 = *(const uint4*)(base + (((cc + 1) ^ (row & 7)) << 2));
        u32 q[8] = {d0.x,d0.y,d0.z,d0.w,d1.x,d1.y,d1.z,d1.w};
        #pragma unroll
        for (int j = 0; j < 8; ++j) {
          ah[rt][j] = (short)(q[j] >> 16);
          al[rt][j] = (short)(q[j] & 0xffff);
        }
      }
      #pragma unroll
      for (int ct = 0; ct < 4; ++ct)
        #pragma unroll
        for (int rt = 0; rt < 4; ++rt) {
          acc[rt][ct] = __builtin_amdgcn_mfma_f32_16x16x32_bf16(ah[rt], bh[pb][ct],  acc[rt][ct], 0,0,0);
          acc[rt][ct] = __builtin_amdgcn_mfma_f32_16x16x32_bf16(al[rt], bh[pb][ct],  acc[rt][ct], 0,0,0);
          acc[rt][ct] = __builtin_amdgcn_mfma_f32_16x16x32_bf16(ah[rt], blo[pb][ct], acc[rt][ct], 0,0,0);
        }
    }
    const float* bptr = (lyr < nbs) ? (bs + lyr*256) : bl;
    const bool dorelu = (lyr < L-1) || (FIN == 1);
    #pragma unroll
    for (int ct = 0; ct < 4; ++ct) {
      float bv = bptr[cg*64 + ct*16 + lr];
      #pragma unroll
      for (int rt = 0; rt < 4; ++rt)
        #pragma unroll
        for (int g = 0; g < 4; ++g) {
          float xv = acc[rt][ct][g] + bv;
          acc[rt][ct][g] = dorelu ? fmaxf(xv, 0.f) : xv;
        }
    }
    if (lyr == L-1) break;
    __syncthreads();
    #pragma unroll
    for (int ct = 0; ct < 4; ++ct) {
      int n = cg*64 + ct*16 + lr;
      #pragma unroll
      for (int rt = 0; rt < 4; ++rt)
        #pragma unroll
        for (int g = 0; g < 4; ++g) {
          int row = rt*16 + lk*4 + g;
          act[row*256 + (((n >> 2) ^ (row & 7)) << 2) + (n & 3)] = packhl(acc[rt][ct][g]);
        }
    }
  }

  if (FIN == 0) {
    #pragma unroll
    for (int ct = 0; ct < 4; ++ct) {
      int n = cg*64 + ct*16 + lr;
      #pragma unroll
      for (int rt = 0; rt < 4; ++rt)
        #pragma unroll
        for (int g = 0; g < 4; ++g) {
          long m = m0 + rt*16 + lk*4 + g;
          if (OUTP) ((u32*)Cout)[m*256 + n] = packhl(acc[rt][ct][g]);
          else      Cout[m*256 + n] = acc[rt][ct][g];
        }
    }
  } else {
    float part[4][4];
    #pragma unroll
    for (int rt = 0; rt < 4; ++rt)
      #pragma unroll
      for (int g = 0; g < 4; ++g) part[rt][g] = 0.f;
    #pragma unroll
    for (int ct = 0; ct < 4; ++ct) {
      float vw = vWl[cg*64 + ct*16 + lr];
      #pragma unroll
      for (int rt = 0; rt < 4; ++rt)
        #pragma unroll
        for (int g = 0; g < 4; ++g) part[rt][g] += acc[rt][ct][g] * vw;
    }
    #pragma unroll
    for (int o = 1; o < 16; o <<= 1)
      #pragma unroll
      for (int rt = 0; rt < 4; ++rt)
        #pragma unroll
        for (int g = 0; g < 4; ++g) part[rt][g] += __shfl_xor(part[rt][g], o, 64);
    __syncthreads();
    float* ep = (float*)act;                      // [4][64]
    if ((l & 15) == 0) {
      #pragma unroll
      for (int rt = 0; rt < 4; ++rt)
        #pragma unroll
        for (int g = 0; g < 4; ++g)
          ep[cg*64 + rt*16 + lk*4 + g] = part[rt][g];
    }
    __syncthreads();
    if (tid < 64)
      eout[m0 + tid] = ep[tid] + ep[64 + tid] + ep[128 + tid] + ep[192 + tid] + vbl[0];
  }
}

// ---------------------------------------------------------------------------
// Fused softmax + context over henc (t-major, packed hi/lo). e[t*CB + b].
// ---------------------------------------------------------------------------
__global__ __launch_bounds__(256,2) void k_attn(const float* __restrict__ e,
    const u32* __restrict__ henc, float* __restrict__ ct, int CB)
{
  __shared__ float as[512];
  __shared__ float red[8];
  const int b = blockIdx.x, tid = threadIdx.x;
  const int lane = tid & 63, w = tid >> 6;
  float v0 = e[(size_t)tid*CB + b];
  float v1 = e[(size_t)(tid + 256)*CB + b];
  float m = fmaxf(v0, v1);
  #pragma unroll
  for (int o = 32; o; o >>= 1) m = fmaxf(m, __shfl_xor(m, o, 64));
  if (!lane) red[w] = m;
  __syncthreads();
  m = fmaxf(fmaxf(red[0], red[1]), fmaxf(red[2], red[3]));
  float x0 = expf(v0 - m), x1 = expf(v1 - m);
  float sm = x0 + x1;
  #pragma unroll
  for (int o = 32; o; o >>= 1) sm += __shfl_xor(sm, o, 64);
  if (!lane) red[4 + w] = sm;
  __syncthreads();
  float inv = 1.f / (red[4] + red[5] + red[6] + red[7]);
  as[tid] = x0 * inv;
  as[256 + tid] = x1 * inv;
  __syncthreads();
  float acc = 0.f;
  const u32* ep = henc + (size_t)(CB + b)*256 + tid;   // slot 1, unit=tid
  const size_t ts = (size_t)CB * 256;
  #pragma unroll 8
  for (int t = 0; t < 512; ++t) acc += as[t] * unpackhl(ep[t*ts]);
  ct[b*H_ + tid] = acc;
}

__global__ __launch_bounds__(256,2) void k_dec_cell(
    const float* __restrict__ ct, float* __restrict__ s, const float* __restrict__ dWt,
    const float* __restrict__ bih, const float* __restrict__ bhh,
    float* __restrict__ dec, int step)
{
  __shared__ float xt[4][516];
  const int tid = threadIdx.x;
  const int b0 = blockIdx.x * 4;
  for (int f = tid; f < 4*128; f += 256) {
    int bb = f >> 7, k4 = f & 127;
    float4 v = (k4 < 64) ? *(const float4*)(ct + (b0+bb)*H_ + k4*4)
                         : *(const float4*)(s  + (b0+bb)*H_ + (k4-64)*4);
    *(float4*)(&xt[bb][k4*4]) = v;
  }
  __syncthreads();
  const int u = tid;
  float ai[4], ag[4], ao[4];
  #pragma unroll
  for (int bb = 0; bb < 4; ++bb) { ai[bb]=0.f; ag[bb]=0.f; ao[bb]=0.f; }
  #pragma unroll 4
  for (int k = 0; k < 512; ++k) {
    float wi = dWt[k*768 + u];
    float wg = dWt[k*768 + 256 + u];
    float wo = dWt[k*768 + 512 + u];
    #pragma unroll
    for (int bb = 0; bb < 4; ++bb) {
      float xv = xt[bb][k];
      ai[bb] += xv*wi; ag[bb] += xv*wg; ao[bb] += xv*wo;
    }
  }
  float bi = bih[u]       + bhh[u];
  float bg = bih[512 + u] + bhh[512 + u];
  float bo = bih[768 + u] + bhh[768 + u];
  #pragma unroll
  for (int bb = 0; bb < 4; ++bb) {
    int b = b0 + bb;
    float cn = sigm(ai[bb] + bi) * tanhf(ag[bb] + bg);
    float hn = sigm(ao[bb] + bo) * tanhf(cn);
    s[b*H_ + u] = hn;
    dec[((size_t)b*OL_ + step)*H_ + u] = hn;
  }
}

__global__ __launch_bounds__(256,2) void k_outproj(
    const float* __restrict__ dec, const float* __restrict__ oW,
    const float* __restrict__ ob, float* __restrict__ out)
{
  const int tid = threadIdx.x;
  const int m0 = blockIdx.x * 16;
  const int d = tid & 63, rr = tid >> 6;
  float bv = ob[d];
  for (int p = 0; p < 4; ++p) {
    int m = m0 + p*4 + rr;
    const float* ar = dec + (size_t)m*H_;
    float acc = bv;
    #pragma unroll 4
    for (int k = 0; k < H_; ++k) acc += ar[k] * oW[k*64 + d];
    out[(size_t)m*64 + d] = acc;
  }
}

// ---------------------------------------------------------------------------
extern "C" void kernel_launch(void* const* d_in, const int* in_sizes, int n_in,
                              void* d_out, int out_size, void* d_ws, size_t ws_size,
                              hipStream_t stream)
{
  (void)in_sizes; (void)n_in;
  const float* x    = (const float*)d_in[0];
  const float* inW  = (const float*)d_in[1];
  const float* inb  = (const float*)d_in[2];
  const float* eWih = (const float*)d_in[3];
  const float* eWhh = (const float*)d_in[4];
  const float* ebih = (const float*)d_in[5];
  const float* ebhh = (const float*)d_in[6];
  const float* dWih = (const float*)d_in[7];
  const float* dbih = (const float*)d_in[9];
  const float* dbhh = (const float*)d_in[10];
  const float* wWs  = (const float*)d_in[11];
  const float* wbs  = (const float*)d_in[12];
  const float* wWl  = (const float*)d_in[13];
  const float* wbl  = (const float*)d_in[14];
  const float* uWs  = (const float*)d_in[15];
  const float* ubs  = (const float*)d_in[16];
  const float* uWl  = (const float*)d_in[17];
  const float* ubl  = (const float*)d_in[18];
  const float* vWs  = (const float*)d_in[19];
  const float* vbs  = (const float*)d_in[20];
  const float* vWl  = (const float*)d_in[21];
  const float* vbl  = (const float*)d_in[22];
  const float* oW   = (const float*)d_in[23];
  const float* ob   = (const float*)d_in[24];
  float* out = (float*)d_out;

  hipFuncSetAttribute((const void*)k_mlp<0,0,0>, hipFuncAttributeMaxDynamicSharedMemorySize, 65536);
  hipFuncSetAttribute((const void*)k_mlp<2,0,1>, hipFuncAttributeMaxDynamicSharedMemorySize, 65536);
  hipFuncSetAttribute((const void*)k_mlp<3,1,0>, hipFuncAttributeMaxDynamicSharedMemorySize, 65536);

  const int CB = 128;
  const size_t hsz = (size_t)(T_+1)*CB*256;     // u32 units per chunk
  const size_t avail = ws_size / 4;
  auto need = [&](int nc) -> size_t {
    return (size_t)nc*hsz                 // henc
         + (size_t)CB*T_*256/1            // whs (u32, 4B units)... stored as u32: CB*T*256 u32
         - (size_t)CB*T_*256 + (size_t)CB*T_*256   // (kept explicit below)
         + (size_t)CB*3328 + 1300000ull;
  };
  // explicit: whs_u32 = CB*T*256 u32 units
  auto needf = [&](int nc) -> size_t {
    return (size_t)nc*hsz + (size_t)CB*T_*256 + (size_t)CB*3328 + 1300000ull;
  };
  (void)need;
  int NC = (needf(2) <= avail) ? 2 : 1;
  if (needf(NC) > avail) { hipMemsetAsync(d_out, 0, (size_t)out_size*4, stream); return; }

  float* wsf = (float*)d_ws;
  size_t o = 0;
  u32* henc = (u32*)(wsf + o);  o += (size_t)NC*hsz;
  u32* whsP = (u32*)(wsf + o);  o += (size_t)CB*T_*256;     // packed whs
  float* sbuf= wsf + o;  o += (size_t)CB*256;
  float* us  = wsf + o;  o += (size_t)CB*256;
  float* ctx = wsf + o;  o += (size_t)CB*256;
  float* dec = wsf + o;  o += (size_t)CB*2048;
  float* e   = wsf + o;  o += (size_t)CB*512;
  float* WpT = wsf + o;  o += 65536;
  float* bp  = wsf + o;  o += 1024;
  float* dWt = wsf + o;  o += 393216;
  u16* whhFL = (u16*)(wsf + o);  o += 262144;
  u16* wpFL  = (u16*)(wsf + o);  o += 65536;
  u16* mlpFL = (u16*)(wsf + o);

  // ---- weight preps (chunk-invariant)
  k_wpt<<<256, 256, 0, stream>>>(inW, eWih, WpT);
  k_bp <<<4,   256, 0, stream>>>(inb, eWih, ebih, ebhh, bp);
  k_dwt<<<1536,256, 0, stream>>>(dWih, dWt);
  k_whhfl<<<1024,256,0,stream>>>(eWhh, whhFL);
  k_wpfl <<<256, 256,0,stream>>>(WpT, wpFL);
  k_wall <<<dim3(256,15), 256, 0, stream>>>(wWs, wWl, uWs, uWl, vWs, mlpFL);

  const int gBig = CB * 8;            // (CB*T)/64 row-tiles
  const int gU   = CB / 64;
  const int cbm1 = CB - 1;

  for (int c0 = 0; c0 < B_; c0 += CB*NC) {
    // zero all henc slots: data-as-flag requires clean buffers
    hipMemsetAsync(henc, 0, (size_t)NC*hsz*4, stream);

    // ---- concurrent chunk encoders (one launch, grid.z = NC)
    k_enc<<<dim3(CB/16, 8, NC), 256, 0, stream>>>(
        x + (size_t)c0*T_*DIN_, whhFL, wpFL, bp, henc, CB);

    for (int z = 0; z < NC; ++z) {
      int c = c0 + z*CB;
      u32* hz = henc + (size_t)z*hsz;
      float* outc = out + (size_t)c*OL_*DOUT_;

      hipMemsetAsync(sbuf, 0, (size_t)CB*1024, stream);   // decode s0 = 0

      // ---- whs = w_mlp(enc), packed output
      k_mlp<2,0,1><<<gBig, 256, 65536, stream>>>((const float*)(hz + (size_t)CB*256),
                                                 nullptr, mlpFL, wbs, wbl,
                                                 (float*)whsP, nullptr, nullptr, nullptr, 4, 3, 0);

      // ---- decode loop
      for (int step = 0; step < OL_; ++step) {
        k_mlp<0,0,0><<<gU, 256, 65536, stream>>>(sbuf, nullptr, mlpFL + 4ull*131072, ubs, ubl,
                                                 us, nullptr, nullptr, nullptr, 4, 3, 0);
        k_mlp<3,1,0><<<gBig, 256, 65536, stream>>>((const float*)whsP, us, mlpFL + 8ull*131072,
                                                   vbs, nullptr, nullptr, e, vWl, vbl, 7, 7, cbm1);
        k_attn<<<CB, 256, 0, stream>>>(e, hz, ctx, CB);
        k_dec_cell<<<CB/4, 256, 0, stream>>>(ctx, sbuf, dWt, dbih, dbhh, dec, step);
      }
      k_outproj<<<CB/2, 256, 0, stream>>>(dec, oW, ob, outc);
    }
  }
}

// Round 10
// 18679.369 us; speedup vs baseline: 1.5016x; 1.0278x over previous
//
#include <hip/hip_runtime.h>
#include <math.h>

#define B_    512
#define T_    512
#define H_    256
#define DIN_  64
#define OL_   8
#define DOUT_ 64

#define CBv   128
#define HSTR  32768          // CBv*256 u32 per henc slot

typedef unsigned short u16;
typedef unsigned int u32;
typedef unsigned long long ull;
typedef __attribute__((ext_vector_type(8))) short short8;   // 8 bf16 (MFMA A/B frag)
typedef __attribute__((ext_vector_type(4))) float f32x4;    // MFMA C/D frag (16x16)

static __device__ __forceinline__ float sigm(float x){ return 1.0f/(1.0f + expf(-x)); }
static __device__ __forceinline__ float bf2f(u16 h){
  u32 u = ((u32)h) << 16; float f; __builtin_memcpy(&f, &u, 4); return f;
}
static __device__ __forceinline__ u16 f2bf(float f){        // RNE
  u32 u; __builtin_memcpy(&u, &f, 4);
  u = (u + 0x7fffu + ((u >> 16) & 1u)) >> 16;
  return (u16)u;
}
static __device__ __forceinline__ u32 packhl(float f){      // hi<<16 | lo
  u16 h = f2bf(f);
  u16 lo = f2bf(f - bf2f(h));
  return ((u32)h << 16) | (u32)lo;
}
static __device__ __forceinline__ float unpackhl(u32 w){
  return bf2f((u16)(w >> 16)) + bf2f((u16)(w & 0xffff));
}
static __device__ __forceinline__ u32 al(const u32* p){
  return __hip_atomic_load(p, __ATOMIC_RELAXED, __HIP_MEMORY_SCOPE_AGENT);
}
static __device__ __forceinline__ void as_(u32* p, u32 v){
  __hip_atomic_store(p, v, __ATOMIC_RELAXED, __HIP_MEMORY_SCOPE_AGENT);
}

// ---------------------------------------------------------------------------
// Weight preps (unchanged, proven)
// ---------------------------------------------------------------------------
__global__ void k_wpt(const float* __restrict__ inW, const float* __restrict__ Wih,
                      float* __restrict__ WpT)
{
  int gid = blockIdx.x * 256 + threadIdx.x;   // 65536
  int c = gid >> 6, d = gid & 63;
  const float* wr = Wih + c * H_;
  const float* ir = inW + d * H_;
  float acc = 0.f;
  #pragma unroll 4
  for (int e = 0; e < H_; e += 4) {
    float4 av = *(const float4*)(ir + e);
    float4 bv = *(const float4*)(wr + e);
    acc += av.x*bv.x + av.y*bv.y + av.z*bv.z + av.w*bv.w;
  }
  WpT[c*64 + d] = acc;
}

__global__ void k_bp(const float* __restrict__ inb, const float* __restrict__ Wih,
                     const float* __restrict__ bih, const float* __restrict__ bhh,
                     float* __restrict__ bp)
{
  int c = blockIdx.x * 256 + threadIdx.x;   // 1024
  const float* wr = Wih + c * H_;
  float acc = bih[c] + bhh[c];
  for (int e = 0; e < H_; ++e) acc += inb[e] * wr[e];
  bp[c] = acc;
}

__global__ void k_dwt(const float* __restrict__ dWih, float* __restrict__ dWt)
{
  int gid = blockIdx.x * 256 + threadIdx.x;   // 393216
  int j = gid >> 9, k = gid & 511;
  int row = (j < 256) ? j : (j + 256);
  dWt[k*768 + j] = dWih[row*512 + k];
}

__global__ void k_wall(const float* __restrict__ wWs, const float* __restrict__ wWl,
                       const float* __restrict__ uWs, const float* __restrict__ uWl,
                       const float* __restrict__ vWs, u16* __restrict__ outb)
{
  int lyr = blockIdx.y;
  const float* W = (lyr < 3)  ? wWs + lyr*65536
                 : (lyr == 3) ? wWl
                 : (lyr < 7)  ? uWs + (lyr-4)*65536
                 : (lyr == 7) ? uWl
                 :              vWs + (lyr-8)*65536;
  u16* out = outb + (size_t)lyr*131072;
  int gid = blockIdx.x * 256 + threadIdx.x;   // 65536
  int k = gid & 255, n = gid >> 8;
  float v = W[k*256 + n];
  int s = k >> 5, j = k & 7;
  int lane = (((k >> 3) & 3) << 4) | (n & 15);
  int fl = ((s*16) + (n >> 4))*512 + lane*8 + j;
  u16 h = f2bf(v);
  out[fl] = h;
  out[65536 + fl] = f2bf(v - bf2f(h));
}

__global__ void k_whhfl(const float* __restrict__ Whh, u16* __restrict__ out)
{
  int gid = blockIdx.x * 256 + threadIdx.x;   // 262144
  int j = gid & 7, l = (gid >> 3) & 63, ctg = (gid >> 9) & 63, s = gid >> 15;
  int k = s*32 + (l >> 4)*8 + j;
  int wv = ctg >> 2, g = ctg & 3;
  int row = g*256 + wv*16 + (l & 15);
  float v = Whh[row*256 + k];
  int fl = (s*64 + ctg)*512 + l*8 + j;
  u16 h = f2bf(v);
  out[fl] = h;
  out[262144 + fl] = f2bf(v - bf2f(h));
}

__global__ void k_wpfl(const float* __restrict__ WpT, u16* __restrict__ out)
{
  int gid = blockIdx.x * 256 + threadIdx.x;   // 65536
  int j = gid & 7, l = (gid >> 3) & 63, ctg = (gid >> 9) & 63, s = gid >> 15;
  int k = s*32 + (l >> 4)*8 + j;              // < 64
  int wv = ctg >> 2, g = ctg & 3;
  int row = g*256 + wv*16 + (l & 15);
  float v = WpT[row*64 + k];
  int fl = (s*64 + ctg)*512 + l*8 + j;
  u16 h = f2bf(v);
  out[fl] = h;
  out[65536 + fl] = f2bf(v - bf2f(h));
}

// ---------------------------------------------------------------------------
// Clustered persistent encoder, DATA-AS-FLAG (r9, proven).
// ---------------------------------------------------------------------------
__global__ __launch_bounds__(256,1) void k_enc(
    const float* __restrict__ x, const u16* __restrict__ whhFL,
    const u16* __restrict__ wpFL, const float* __restrict__ bp,
    u32* __restrict__ henc)
{
  __shared__ float G[2][16][32][4];
  const int tid = threadIdx.x, l = tid & 63, wv = tid >> 6;
  const int lr = l & 15, lk = l >> 4;
  const int rg = blockIdx.x, bg = blockIdx.y, z = blockIdx.z;
  const int ug2 = wv >> 1;
  const int g0 = (wv & 1) * 2;
  const int u16g = bg*2 + ug2;

  short8 whH[8][2], whL[8][2], wpH[2][2], wpL[2][2];
  #pragma unroll
  for (int s = 0; s < 8; ++s)
    #pragma unroll
    for (int c = 0; c < 2; ++c) {
      int ctg = u16g*4 + g0 + c;
      whH[s][c] = *(const short8*)(whhFL + ((size_t)(s*64 + ctg))*512 + l*8);
      whL[s][c] = *(const short8*)(whhFL + 262144 + ((size_t)(s*64 + ctg))*512 + l*8);
    }
  #pragma unroll
  for (int s = 0; s < 2; ++s)
    #pragma unroll
    for (int c = 0; c < 2; ++c) {
      int ctg = u16g*4 + g0 + c;
      wpH[s][c] = *(const short8*)(wpFL + ((size_t)(s*64 + ctg))*512 + l*8);
      wpL[s][c] = *(const short8*)(wpFL + 65536 + ((size_t)(s*64 + ctg))*512 + l*8);
    }
  const int ul = tid & 31, er0 = tid >> 5;
  float bb[4];
  #pragma unroll
  for (int g = 0; g < 4; ++g) bb[g] = bp[g*256 + bg*32 + ul];
  float cs[2] = {0.f, 0.f};

  u32* hz = henc + (size_t)z * (size_t)(T_+1) * HSTR;
  const float* xrow = x + ((size_t)(z*CBv + rg*16 + lr)*T_)*DIN_ + lk*8;

  for (int t = 0; t < T_; ++t) {
    float4 xv0 = *(const float4*)(xrow);
    float4 xv1 = *(const float4*)(xrow + 4);
    float4 xv2 = *(const float4*)(xrow + 32);
    float4 xv3 = *(const float4*)(xrow + 36);
    xrow += DIN_;

    const ull* hb = (const ull*)(hz + (size_t)t*HSTR + (size_t)(rg*16 + lr)*256);
    ull hq[8][4];
    #pragma unroll
    for (int s = 0; s < 8; ++s)
      #pragma unroll
      for (int q = 0; q < 4; ++q)
        hq[s][q] = __hip_atomic_load(hb + s*16 + lk*4 + q,
                                     __ATOMIC_RELAXED, __HIP_MEMORY_SCOPE_AGENT);
    if (t) {
      for (;;) {
        bool ok = true;
        #pragma unroll
        for (int s = 0; s < 8; ++s)
          #pragma unroll
          for (int q = 0; q < 4; ++q) {
            u32 a = (u32)hq[s][q], b = (u32)(hq[s][q] >> 32);
            ok = ok && (a != 0u) && (b != 0u);
          }
        if (__all(ok)) break;
        __builtin_amdgcn_s_sleep(1);
        #pragma unroll
        for (int s = 0; s < 8; ++s)
          #pragma unroll
          for (int q = 0; q < 4; ++q)
            hq[s][q] = __hip_atomic_load(hb + s*16 + lk*4 + q,
                                         __ATOMIC_RELAXED, __HIP_MEMORY_SCOPE_AGENT);
      }
    }

    f32x4 acc[2];
    acc[0] = (f32x4){0.f,0.f,0.f,0.f};
    acc[1] = (f32x4){0.f,0.f,0.f,0.f};

    #pragma unroll
    for (int s = 0; s < 2; ++s) {
      float vv[8];
      if (s == 0) { vv[0]=xv0.x;vv[1]=xv0.y;vv[2]=xv0.z;vv[3]=xv0.w;vv[4]=xv1.x;vv[5]=xv1.y;vv[6]=xv1.z;vv[7]=xv1.w; }
      else        { vv[0]=xv2.x;vv[1]=xv2.y;vv[2]=xv2.z;vv[3]=xv2.w;vv[4]=xv3.x;vv[5]=xv3.y;vv[6]=xv3.z;vv[7]=xv3.w; }
      short8 ah, al2;
      #pragma unroll
      for (int j = 0; j < 8; ++j) {
        u16 h = f2bf(vv[j]);
        ah[j] = (short)h;
        al2[j] = (short)f2bf(vv[j] - bf2f(h));
      }
      #pragma unroll
      for (int c = 0; c < 2; ++c) {
        acc[c] = __builtin_amdgcn_mfma_f32_16x16x32_bf16(ah,  wpH[s][c], acc[c], 0,0,0);
        acc[c] = __builtin_amdgcn_mfma_f32_16x16x32_bf16(al2, wpH[s][c], acc[c], 0,0,0);
        acc[c] = __builtin_amdgcn_mfma_f32_16x16x32_bf16(ah,  wpL[s][c], acc[c], 0,0,0);
      }
    }
    #pragma unroll
    for (int s = 0; s < 8; ++s) {
      short8 ah, al2;
      #pragma unroll
      for (int q = 0; q < 4; ++q) {
        u32 w0 = (u32)hq[s][q], w1 = (u32)(hq[s][q] >> 32);
        ah[q*2]   = (short)(w0 >> 16); al2[q*2]   = (short)(w0 & 0xffff);
        ah[q*2+1] = (short)(w1 >> 16); al2[q*2+1] = (short)(w1 & 0xffff);
      }
      #pragma unroll
      for (int c = 0; c < 2; ++c) {
        acc[c] = __builtin_amdgcn_mfma_f32_16x16x32_bf16(ah,  whH[s][c], acc[c], 0,0,0);
        acc[c] = __builtin_amdgcn_mfma_f32_16x16x32_bf16(al2, whH[s][c], acc[c], 0,0,0);
        acc[c] = __builtin_amdgcn_mfma_f32_16x16x32_bf16(ah,  whL[s][c], acc[c], 0,0,0);
      }
    }

    const int p = t & 1;
    #pragma unroll
    for (int c = 0; c < 2; ++c)
      #pragma unroll
      for (int j = 0; j < 4; ++j)
        G[p][lk*4 + j][ug2*16 + lr][g0 + c] = acc[c][j];
    __syncthreads();

    #pragma unroll
    for (int pp = 0; pp < 2; ++pp) {
      int row = er0 + pp*8;
      float4 gq = *(const float4*)&G[p][row][ul][0];
      float gi = gq.x + bb[0], gf = gq.y + bb[1];
      float gg = gq.z + bb[2], go = gq.w + bb[3];
      float cn = sigm(gf)*cs[pp] + sigm(gi)*tanhf(gg);
      float hn = sigm(go)*tanhf(cn);
      cs[pp] = cn;
      as_(hz + (size_t)(t+1)*HSTR + (size_t)(rg*16 + row)*256 + bg*32 + ul,
          packhl(hn) | 1u);
    }
  }
}

// ---------------------------------------------------------------------------
// MLP layer-loop core: act (LDS, [64][256] u32 packhl chunk-swizzled) holds
// the tile; runs L layers streaming weights; leaves FINAL activations in act.
// 256 thr = 4 waves (col-groups).
// ---------------------------------------------------------------------------
static __device__ __forceinline__ void mlp_core(
    u32* act, const u16* wFL, const float* bs, const float* bl,
    int L, int nbs, bool lastRelu, int tid)
{
  const int l = tid & 63, cg = tid >> 6;
  const int lr = l & 15, lk = l >> 4;
  f32x4 acc[4][4];
  for (int lyr = 0; lyr < L; ++lyr) {
    __syncthreads();                       // staging / prior writeback visible
    const u16* wb = wFL + (size_t)lyr*131072;
    #pragma unroll
    for (int rt = 0; rt < 4; ++rt)
      #pragma unroll
      for (int ct = 0; ct < 4; ++ct) acc[rt][ct] = (f32x4){0.f,0.f,0.f,0.f};

    short8 bh[2][4], blo[2][4];
    #pragma unroll
    for (int ct = 0; ct < 4; ++ct) {
      const u16* bfp = wb + ((size_t)(cg*4 + ct))*512 + l*8;
      bh[0][ct]  = *(const short8*)bfp;
      blo[0][ct] = *(const short8*)(bfp + 65536);
    }
    #pragma unroll
    for (int s = 0; s < 8; ++s) {
      const int pb = s & 1, nb = pb ^ 1;
      if (s < 7) {
        #pragma unroll
        for (int ct = 0; ct < 4; ++ct) {
          const u16* bfp = wb + ((size_t)((s+1)*16 + cg*4 + ct))*512 + l*8;
          bh[nb][ct]  = *(const short8*)bfp;
          blo[nb][ct] = *(const short8*)(bfp + 65536);
        }
      }
      short8 ah[4], al2[4];
      #pragma unroll
      for (int rt = 0; rt < 4; ++rt) {
        int row = rt*16 + lr;
        int cc = s*8 + lk*2;
        const u32* base = act + row*256;
        uint4 d0 = *(const uint4*)(base + (((cc    ) ^ (row & 7)) << 2));
        uint4 d1 = *(const uint4*)(base + (((cc + 1) ^ (row & 7)) << 2));
        u32 q[8] = {d0.x,d0.y,d0.z,d0.w,d1.x,d1.y,d1.z,d1.w};
        #pragma unroll
        for (int j = 0; j < 8; ++j) {
          ah[rt][j]  = (short)(q[j] >> 16);
          al2[rt][j] = (short)(q[j] & 0xffff);
        }
      }
      #pragma unroll
      for (int ct = 0; ct < 4; ++ct)
        #pragma unroll
        for (int rt = 0; rt < 4; ++rt) {
          acc[rt][ct] = __builtin_amdgcn_mfma_f32_16x16x32_bf16(ah[rt],  bh[pb][ct],  acc[rt][ct], 0,0,0);
          acc[rt][ct] = __builtin_amdgcn_mfma_f32_16x16x32_bf16(al2[rt], bh[pb][ct],  acc[rt][ct], 0,0,0);
          acc[rt][ct] = __builtin_amdgcn_mfma_f32_16x16x32_bf16(ah[rt],  blo[pb][ct], acc[rt][ct], 0,0,0);
        }
    }
    const float* bptr = (lyr < nbs) ? (bs + lyr*256) : bl;
    const bool dorelu = (lyr < L-1) || lastRelu;
    #pragma unroll
    for (int ct = 0; ct < 4; ++ct) {
      float bv = bptr[cg*64 + ct*16 + lr];
      #pragma unroll
      for (int rt = 0; rt < 4; ++rt)
        #pragma unroll
        for (int g = 0; g < 4; ++g) {
          float xv = acc[rt][ct][g] + bv;
          acc[rt][ct][g] = dorelu ? fmaxf(xv, 0.f) : xv;
        }
    }
    __syncthreads();                      // all reads of act done
    #pragma unroll
    for (int ct = 0; ct < 4; ++ct) {
      int n = cg*64 + ct*16 + lr;
      #pragma unroll
      for (int rt = 0; rt < 4; ++rt)
        #pragma unroll
        for (int g = 0; g < 4; ++g) {
          int row = rt*16 + lk*4 + g;
          act[row*256 + (((n >> 2) ^ (row & 7)) << 2) + (n & 3)] = packhl(acc[rt][ct][g]);
        }
    }
  }
  __syncthreads();                        // final activations visible
}

// ---------------------------------------------------------------------------
// MEGA decode kernel: whs-MLP + 8 x {u-MLP -> v-MLP -> attn -> cell+outproj}
// in ONE launch. 256 blocks x 256 thr, 64KB LDS, co-resident.
// Sync: step-indexed data-as-flag (marked fp32, LSB) for e/ctx/s;
//       2-word release/acquire flag for us. whs tiles are block-local.
// Roles: u = blocks 0,1; v = all (tiles bid+256k); attn = 64..191 (1 row);
//        cell+outproj = 224..255 (4 rows).
// ---------------------------------------------------------------------------
__global__ __launch_bounds__(256,1) void k_dec_all(
    const u32* __restrict__ henc, const u16* __restrict__ mlpFL,
    const float* __restrict__ wbs, const float* __restrict__ wbl,
    const float* __restrict__ ubs, const float* __restrict__ ubl,
    const float* __restrict__ vbs, const float* __restrict__ vWl,
    const float* __restrict__ vbl,
    const float* __restrict__ dWt, const float* __restrict__ dbih,
    const float* __restrict__ dbhh,
    const float* __restrict__ oW, const float* __restrict__ ob,
    u32* __restrict__ whsP, u32* __restrict__ usb, u32* __restrict__ usflag,
    u32* __restrict__ eS, u32* __restrict__ ctxS, u32* __restrict__ sS,
    float* __restrict__ outc)
{
  extern __shared__ u32 act[];            // 64KB: [64][256] u32 / attn / cell
  __shared__ float red[8];
  const int bid = blockIdx.x, tid = threadIdx.x;
  const u16* wFLw = mlpFL;
  const u16* wFLu = mlpFL + 4*131072;
  const u16* wFLv = mlpFL + 8*131072;
  float sprev[4] = {0.f, 0.f, 0.f, 0.f};  // cell blocks' s-state (registers)

  // ======== whs stage: 4 block-local tiles (no cross-block sync) ========
  for (int k = 0; k < 4; ++k) {
    long m0t = (long)(bid + 256*k) * 64;
    __syncthreads();
    for (int i = tid; i < 4096; i += 256) {
      int row = i >> 6, c16 = i & 63;
      long m = m0t + row;
      uint4 pk = *(const uint4*)(henc + HSTR + m*256 + c16*4);
      *((uint4*)(act + row*256 + ((c16 ^ (row & 7)) << 2))) = pk;
    }
    mlp_core(act, wFLw, wbs, wbl, 4, 3, false, tid);
    for (int i = tid; i < 4096; i += 256) {
      int row = i >> 6, c16 = i & 63;
      long m = m0t + row;
      uint4 pk = *((const uint4*)(act + row*256 + ((c16 ^ (row & 7)) << 2)));
      *(uint4*)(whsP + m*256 + c16*4) = pk;
    }
  }

  // ======== decode steps ========
  for (int s = 0; s < OL_; ++s) {
    // ---- u-stage (blocks 0,1): s[s] -> us[s] (packed), release flag
    if (bid < 2) {
      long m0t = (long)bid * 64;
      __syncthreads();
      for (int i = tid; i < 4096; i += 256) {
        int row = i >> 6, c16 = i & 63;
        const u32* sp = sS + (size_t)s*32768 + (m0t + row)*256 + c16*4;
        u32 w0 = al(sp), w1 = al(sp+1), w2 = al(sp+2), w3 = al(sp+3);
        if (s) {
          while (!(w0 && w1 && w2 && w3)) {
            __builtin_amdgcn_s_sleep(1);
            w0 = al(sp); w1 = al(sp+1); w2 = al(sp+2); w3 = al(sp+3);
          }
        }
        uint4 pk = { packhl(__uint_as_float(w0)), packhl(__uint_as_float(w1)),
                     packhl(__uint_as_float(w2)), packhl(__uint_as_float(w3)) };
        *((uint4*)(act + row*256 + ((c16 ^ (row & 7)) << 2))) = pk;
      }
      mlp_core(act, wFLu, ubs, ubl, 4, 3, false, tid);
      for (int i = tid; i < 4096; i += 256) {
        int row = i >> 6, c16 = i & 63;
        uint4 pk = *((const uint4*)(act + row*256 + ((c16 ^ (row & 7)) << 2)));
        *(uint4*)(usb + (size_t)s*32768 + (m0t + row)*256 + c16*4) = pk;
      }
      __syncthreads();                    // drain us stores (vmcnt0 @ barrier)
      if (tid == 0)
        __hip_atomic_store(usflag + s*2 + bid, 1u,
                           __ATOMIC_RELEASE, __HIP_MEMORY_SCOPE_AGENT);
    }

    // ---- wait us ready (all blocks)
    {
      const u32* f0 = usflag + s*2;
      for (;;) {
        u32 a0 = al(f0), a1 = al(f0 + 1);
        if (a0 & a1) break;
        __builtin_amdgcn_s_sleep(2);
      }
      __builtin_amdgcn_fence(__ATOMIC_ACQUIRE, "agent");
    }

    // ---- v-stage: 4 tiles: tanh(whs + us) -> 7 layers -> e (marked)
    for (int k = 0; k < 4; ++k) {
      long m0t = (long)(bid + 256*k) * 64;
      __syncthreads();
      for (int i = tid; i < 4096; i += 256) {
        int row = i >> 6, c16 = i & 63;
        long m = m0t + row;
        uint4 pw = *(const uint4*)(whsP + m*256 + c16*4);
        uint4 uw = *(const uint4*)(usb + (size_t)s*32768 + (m & 127)*256 + c16*4);
        uint4 pk;
        pk.x = packhl(tanhf(unpackhl(pw.x) + unpackhl(uw.x)));
        pk.y = packhl(tanhf(unpackhl(pw.y) + unpackhl(uw.y)));
        pk.z = packhl(tanhf(unpackhl(pw.z) + unpackhl(uw.z)));
        pk.w = packhl(tanhf(unpackhl(pw.w) + unpackhl(uw.w)));
        *((uint4*)(act + row*256 + ((c16 ^ (row & 7)) << 2))) = pk;
      }
      mlp_core(act, wFLv, vbs, vbs, 7, 7, true, tid);
      // e-dot: thread-quad per row
      {
        int r2 = tid >> 2, q = tid & 3;
        float p = 0.f;
        #pragma unroll 8
        for (int j = 0; j < 64; ++j) {
          int n = q*64 + j;
          u32 w = act[r2*256 + (((n >> 2) ^ (r2 & 7)) << 2) + (n & 3)];
          p += unpackhl(w) * vWl[n];
        }
        p += __shfl_xor(p, 1, 64);
        p += __shfl_xor(p, 2, 64);
        if (q == 0)
          as_(eS + (size_t)s*65536 + m0t + r2, __float_as_uint(p + vbl[0]) | 1u);
      }
    }

    // ---- attn (blocks 64..191): row b = bid-64
    if (bid >= 64 && bid < 192) {
      int b = bid - 64;
      __syncthreads();                    // reclaim act
      float* asx = (float*)act;           // [512]
      const u32* ep0 = eS + (size_t)s*65536 + b;
      u32 w0, w1;
      for (;;) {
        w0 = al(ep0 + (size_t)tid*128);
        w1 = al(ep0 + (size_t)(tid + 256)*128);
        if (w0 && w1) break;
        __builtin_amdgcn_s_sleep(1);
      }
      float v0 = __uint_as_float(w0), v1 = __uint_as_float(w1);
      const int lane = tid & 63, wv = tid >> 6;
      float m = fmaxf(v0, v1);
      #pragma unroll
      for (int o = 32; o; o >>= 1) m = fmaxf(m, __shfl_xor(m, o, 64));
      if (!lane) red[wv] = m;
      __syncthreads();
      m = fmaxf(fmaxf(red[0], red[1]), fmaxf(red[2], red[3]));
      float x0 = expf(v0 - m), x1 = expf(v1 - m);
      float sm = x0 + x1;
      #pragma unroll
      for (int o = 32; o; o >>= 1) sm += __shfl_xor(sm, o, 64);
      if (!lane) red[4 + wv] = sm;
      __syncthreads();
      float inv = 1.f / (red[4] + red[5] + red[6] + red[7]);
      asx[tid] = x0 * inv;
      asx[256 + tid] = x1 * inv;
      __syncthreads();
      float accv = 0.f;
      const u32* hp = henc + HSTR + (size_t)b*256 + tid;
      #pragma unroll 8
      for (int t = 0; t < 512; ++t) accv += asx[t] * unpackhl(hp[(size_t)t*HSTR]);
      as_(ctxS + (size_t)s*32768 + b*256 + tid, __float_as_uint(accv) | 1u);
    }

    // ---- cell + outproj (blocks 224..255): rows 4c..4c+3
    if (bid >= 224) {
      int c = bid - 224, b0r = c*4;
      __syncthreads();                    // reclaim act
      float* xt = (float*)act;            // [4][520]
      float cv[4];
      {
        const u32* cp = ctxS + (size_t)s*32768 + (size_t)b0r*256 + tid;
        u32 w0, w1, w2, w3;
        for (;;) {
          w0 = al(cp); w1 = al(cp + 256); w2 = al(cp + 512); w3 = al(cp + 768);
          if (w0 && w1 && w2 && w3) break;
          __builtin_amdgcn_s_sleep(1);
        }
        cv[0] = __uint_as_float(w0); cv[1] = __uint_as_float(w1);
        cv[2] = __uint_as_float(w2); cv[3] = __uint_as_float(w3);
      }
      #pragma unroll
      for (int bb = 0; bb < 4; ++bb) {
        xt[bb*520 + tid] = cv[bb];
        xt[bb*520 + 256 + tid] = sprev[bb];
      }
      __syncthreads();
      float ai[4], ag[4], ao[4];
      #pragma unroll
      for (int bb = 0; bb < 4; ++bb) { ai[bb]=0.f; ag[bb]=0.f; ao[bb]=0.f; }
      #pragma unroll 4
      for (int k = 0; k < 512; ++k) {
        float wi = dWt[k*768 + tid];
        float wg = dWt[k*768 + 256 + tid];
        float wo = dWt[k*768 + 512 + tid];
        #pragma unroll
        for (int bb = 0; bb < 4; ++bb) {
          float xv = xt[bb*520 + k];
          ai[bb] += xv*wi; ag[bb] += xv*wg; ao[bb] += xv*wo;
        }
      }
      float bi = dbih[tid]       + dbhh[tid];
      float bg = dbih[512 + tid] + dbhh[512 + tid];
      float bo = dbih[768 + tid] + dbhh[768 + tid];
      float snew[4];
      #pragma unroll
      for (int bb = 0; bb < 4; ++bb) {
        float cn = sigm(ai[bb] + bi) * tanhf(ag[bb] + bg);
        snew[bb] = sigm(ao[bb] + bo) * tanhf(cn);
        as_(sS + (size_t)(s+1)*32768 + (size_t)(b0r + bb)*256 + tid,
            __float_as_uint(snew[bb]) | 1u);
        sprev[bb] = snew[bb];
      }
      // outproj for these 4 rows, this step
      __syncthreads();
      float* sn = (float*)act;            // [4][256]
      #pragma unroll
      for (int bb = 0; bb < 4; ++bb) sn[bb*256 + tid] = snew[bb];
      __syncthreads();
      int d = tid & 63, rr = tid >> 6;
      float a2 = ob[d];
      #pragma unroll 4
      for (int k = 0; k < 256; ++k) a2 += sn[rr*256 + k] * oW[k*64 + d];
      outc[((size_t)(b0r + rr)*OL_ + s)*64 + d] = a2;
    }
  }
}

// ---------------------------------------------------------------------------
extern "C" void kernel_launch(void* const* d_in, const int* in_sizes, int n_in,
                              void* d_out, int out_size, void* d_ws, size_t ws_size,
                              hipStream_t stream)
{
  (void)in_sizes; (void)n_in;
  const float* x    = (const float*)d_in[0];
  const float* inW  = (const float*)d_in[1];
  const float* inb  = (const float*)d_in[2];
  const float* eWih = (const float*)d_in[3];
  const float* eWhh = (const float*)d_in[4];
  const float* ebih = (const float*)d_in[5];
  const float* ebhh = (const float*)d_in[6];
  const float* dWih = (const float*)d_in[7];
  const float* dbih = (const float*)d_in[9];
  const float* dbhh = (const float*)d_in[10];
  const float* wWs  = (const float*)d_in[11];
  const float* wbs  = (const float*)d_in[12];
  const float* wWl  = (const float*)d_in[13];
  const float* wbl  = (const float*)d_in[14];
  const float* uWs  = (const float*)d_in[15];
  const float* ubs  = (const float*)d_in[16];
  const float* uWl  = (const float*)d_in[17];
  const float* ubl  = (const float*)d_in[18];
  const float* vWs  = (const float*)d_in[19];
  const float* vbs  = (const float*)d_in[20];
  const float* vWl  = (const float*)d_in[21];
  const float* vbl  = (const float*)d_in[22];
  const float* oW   = (const float*)d_in[23];
  const float* ob   = (const float*)d_in[24];
  float* out = (float*)d_out;

  hipFuncSetAttribute((const void*)k_dec_all, hipFuncAttributeMaxDynamicSharedMemorySize, 65536);

  const size_t hsz = (size_t)(T_+1) * HSTR;     // u32 per chunk
  const size_t avail = ws_size / 4;
  auto needf = [&](int nc) -> size_t {
    return (size_t)nc*hsz + 16777216ull /*whsP*/ + 1343552ull /*scratch*/
         + 1770496ull /*preps*/ + 4096;
  };
  int NC = (needf(2) <= avail) ? 2 : 1;
  if (needf(NC) > avail) { hipMemsetAsync(d_out, 0, (size_t)out_size*4, stream); return; }

  float* wsf = (float*)d_ws;
  size_t o = 0;
  u32* henc = (u32*)(wsf + o);  o += (size_t)NC*hsz;
  u32* whsP = (u32*)(wsf + o);  o += 16777216;
  u32* usb  = (u32*)(wsf + o);  o += 262144;       // scratch block start
  u32* usflag = (u32*)(wsf + o); o += 64;
  u32* eS   = (u32*)(wsf + o);  o += 524288;
  u32* ctxS = (u32*)(wsf + o);  o += 262144;
  u32* sS   = (u32*)(wsf + o);  o += 294912;       // scratch block end
  float* WpT = wsf + o;  o += 65536;
  float* bp  = wsf + o;  o += 1024;
  float* dWt = wsf + o;  o += 393216;
  u16* whhFL = (u16*)(wsf + o);  o += 262144;
  u16* wpFL  = (u16*)(wsf + o);  o += 65536;
  u16* mlpFL = (u16*)(wsf + o);                    // 983040 units

  const size_t scratchBytes = (262144ull + 64 + 524288 + 262144 + 294912) * 4;

  // ---- weight preps (chunk-invariant)
  k_wpt<<<256, 256, 0, stream>>>(inW, eWih, WpT);
  k_bp <<<4,   256, 0, stream>>>(inb, eWih, ebih, ebhh, bp);
  k_dwt<<<1536,256, 0, stream>>>(dWih, dWt);
  k_whhfl<<<1024,256,0,stream>>>(eWhh, whhFL);
  k_wpfl <<<256, 256,0,stream>>>(WpT, wpFL);
  k_wall <<<dim3(256,15), 256, 0, stream>>>(wWs, wWl, uWs, uWl, vWs, mlpFL);

  for (int c0 = 0; c0 < B_; c0 += CBv*NC) {
    hipMemsetAsync(henc, 0, (size_t)NC*hsz*4, stream);   // data-as-flag: clean

    // concurrent chunk encoders
    k_enc<<<dim3(CBv/16, 8, NC), 256, 0, stream>>>(
        x + (size_t)c0*T_*DIN_, whhFL, wpFL, bp, henc);

    for (int z = 0; z < NC; ++z) {
      hipMemsetAsync(usb, 0, scratchBytes, stream);      // step-flags clean
      k_dec_all<<<256, 256, 65536, stream>>>(
          henc + (size_t)z*hsz, mlpFL,
          wbs, wbl, ubs, ubl, vbs, vWl, vbl,
          dWt, dbih, dbhh, oW, ob,
          whsP, usb, usflag, eS, ctxS, sS,
          out + (size_t)(c0 + z*CBv)*OL_*DOUT_);
    }
  }
}

// Round 11
// 18629.575 us; speedup vs baseline: 1.5056x; 1.0027x over previous
//
#include <hip/hip_runtime.h>
#include <math.h>

#define B_    512
#define T_    512
#define H_    256
#define DIN_  64
#define OL_   8
#define DOUT_ 64

#define CBv   128
#define HSTR  32768          // CBv*256 u32 per henc slot

typedef unsigned short u16;
typedef unsigned int u32;
typedef unsigned long long ull;
typedef __attribute__((ext_vector_type(8))) short short8;   // 8 bf16 (MFMA A/B frag)
typedef __attribute__((ext_vector_type(4))) float f32x4;    // MFMA C/D frag (16x16)

static __device__ __forceinline__ float sigm(float x){ return 1.0f/(1.0f + expf(-x)); }
static __device__ __forceinline__ float bf2f(u16 h){
  u32 u = ((u32)h) << 16; float f; __builtin_memcpy(&f, &u, 4); return f;
}
static __device__ __forceinline__ u16 f2bf(float f){        // RNE
  u32 u; __builtin_memcpy(&u, &f, 4);
  u = (u + 0x7fffu + ((u >> 16) & 1u)) >> 16;
  return (u16)u;
}
static __device__ __forceinline__ u32 packhl(float f){      // hi<<16 | lo
  u16 h = f2bf(f);
  u16 lo = f2bf(f - bf2f(h));
  return ((u32)h << 16) | (u32)lo;
}
static __device__ __forceinline__ float unpackhl(u32 w){
  return bf2f((u16)(w >> 16)) + bf2f((u16)(w & 0xffff));
}
static __device__ __forceinline__ u32 al(const u32* p){
  return __hip_atomic_load(p, __ATOMIC_RELAXED, __HIP_MEMORY_SCOPE_AGENT);
}
static __device__ __forceinline__ void as_(u32* p, u32 v){
  __hip_atomic_store(p, v, __ATOMIC_RELAXED, __HIP_MEMORY_SCOPE_AGENT);
}

// ---------------------------------------------------------------------------
// Weight preps (unchanged, proven)
// ---------------------------------------------------------------------------
__global__ void k_wpt(const float* __restrict__ inW, const float* __restrict__ Wih,
                      float* __restrict__ WpT)
{
  int gid = blockIdx.x * 256 + threadIdx.x;   // 65536
  int c = gid >> 6, d = gid & 63;
  const float* wr = Wih + c * H_;
  const float* ir = inW + d * H_;
  float acc = 0.f;
  #pragma unroll 4
  for (int e = 0; e < H_; e += 4) {
    float4 av = *(const float4*)(ir + e);
    float4 bv = *(const float4*)(wr + e);
    acc += av.x*bv.x + av.y*bv.y + av.z*bv.z + av.w*bv.w;
  }
  WpT[c*64 + d] = acc;
}

__global__ void k_bp(const float* __restrict__ inb, const float* __restrict__ Wih,
                     const float* __restrict__ bih, const float* __restrict__ bhh,
                     float* __restrict__ bp)
{
  int c = blockIdx.x * 256 + threadIdx.x;   // 1024
  const float* wr = Wih + c * H_;
  float acc = bih[c] + bhh[c];
  for (int e = 0; e < H_; ++e) acc += inb[e] * wr[e];
  bp[c] = acc;
}

__global__ void k_dwt(const float* __restrict__ dWih, float* __restrict__ dWt)
{
  int gid = blockIdx.x * 256 + threadIdx.x;   // 393216
  int j = gid >> 9, k = gid & 511;
  int row = (j < 256) ? j : (j + 256);
  dWt[k*768 + j] = dWih[row*512 + k];
}

__global__ void k_wall(const float* __restrict__ wWs, const float* __restrict__ wWl,
                       const float* __restrict__ uWs, const float* __restrict__ uWl,
                       const float* __restrict__ vWs, u16* __restrict__ outb)
{
  int lyr = blockIdx.y;
  const float* W = (lyr < 3)  ? wWs + lyr*65536
                 : (lyr == 3) ? wWl
                 : (lyr < 7)  ? uWs + (lyr-4)*65536
                 : (lyr == 7) ? uWl
                 :              vWs + (lyr-8)*65536;
  u16* out = outb + (size_t)lyr*131072;
  int gid = blockIdx.x * 256 + threadIdx.x;   // 65536
  int k = gid & 255, n = gid >> 8;
  float v = W[k*256 + n];
  int s = k >> 5, j = k & 7;
  int lane = (((k >> 3) & 3) << 4) | (n & 15);
  int fl = ((s*16) + (n >> 4))*512 + lane*8 + j;
  u16 h = f2bf(v);
  out[fl] = h;
  out[65536 + fl] = f2bf(v - bf2f(h));
}

__global__ void k_whhfl(const float* __restrict__ Whh, u16* __restrict__ out)
{
  int gid = blockIdx.x * 256 + threadIdx.x;   // 262144
  int j = gid & 7, l = (gid >> 3) & 63, ctg = (gid >> 9) & 63, s = gid >> 15;
  int k = s*32 + (l >> 4)*8 + j;
  int wv = ctg >> 2, g = ctg & 3;
  int row = g*256 + wv*16 + (l & 15);
  float v = Whh[row*256 + k];
  int fl = (s*64 + ctg)*512 + l*8 + j;
  u16 h = f2bf(v);
  out[fl] = h;
  out[262144 + fl] = f2bf(v - bf2f(h));
}

__global__ void k_wpfl(const float* __restrict__ WpT, u16* __restrict__ out)
{
  int gid = blockIdx.x * 256 + threadIdx.x;   // 65536
  int j = gid & 7, l = (gid >> 3) & 63, ctg = (gid >> 9) & 63, s = gid >> 15;
  int k = s*32 + (l >> 4)*8 + j;              // < 64
  int wv = ctg >> 2, g = ctg & 3;
  int row = g*256 + wv*16 + (l & 15);
  float v = WpT[row*64 + k];
  int fl = (s*64 + ctg)*512 + l*8 + j;
  u16 h = f2bf(v);
  out[fl] = h;
  out[65536 + fl] = f2bf(v - bf2f(h));
}

// ---------------------------------------------------------------------------
// Clustered persistent encoder, DATA-AS-FLAG (r9, proven; unchanged).
// ---------------------------------------------------------------------------
__global__ __launch_bounds__(256,1) void k_enc(
    const float* __restrict__ x, const u16* __restrict__ whhFL,
    const u16* __restrict__ wpFL, const float* __restrict__ bp,
    u32* __restrict__ henc)
{
  __shared__ float G[2][16][32][4];
  const int tid = threadIdx.x, l = tid & 63, wv = tid >> 6;
  const int lr = l & 15, lk = l >> 4;
  const int rg = blockIdx.x, bg = blockIdx.y, z = blockIdx.z;
  const int ug2 = wv >> 1;
  const int g0 = (wv & 1) * 2;
  const int u16g = bg*2 + ug2;

  short8 whH[8][2], whL[8][2], wpH[2][2], wpL[2][2];
  #pragma unroll
  for (int s = 0; s < 8; ++s)
    #pragma unroll
    for (int c = 0; c < 2; ++c) {
      int ctg = u16g*4 + g0 + c;
      whH[s][c] = *(const short8*)(whhFL + ((size_t)(s*64 + ctg))*512 + l*8);
      whL[s][c] = *(const short8*)(whhFL + 262144 + ((size_t)(s*64 + ctg))*512 + l*8);
    }
  #pragma unroll
  for (int s = 0; s < 2; ++s)
    #pragma unroll
    for (int c = 0; c < 2; ++c) {
      int ctg = u16g*4 + g0 + c;
      wpH[s][c] = *(const short8*)(wpFL + ((size_t)(s*64 + ctg))*512 + l*8);
      wpL[s][c] = *(const short8*)(wpFL + 65536 + ((size_t)(s*64 + ctg))*512 + l*8);
    }
  const int ul = tid & 31, er0 = tid >> 5;
  float bb[4];
  #pragma unroll
  for (int g = 0; g < 4; ++g) bb[g] = bp[g*256 + bg*32 + ul];
  float cs[2] = {0.f, 0.f};

  u32* hz = henc + (size_t)z * (size_t)(T_+1) * HSTR;
  const float* xrow = x + ((size_t)(z*CBv + rg*16 + lr)*T_)*DIN_ + lk*8;

  for (int t = 0; t < T_; ++t) {
    float4 xv0 = *(const float4*)(xrow);
    float4 xv1 = *(const float4*)(xrow + 4);
    float4 xv2 = *(const float4*)(xrow + 32);
    float4 xv3 = *(const float4*)(xrow + 36);
    xrow += DIN_;

    const ull* hb = (const ull*)(hz + (size_t)t*HSTR + (size_t)(rg*16 + lr)*256);
    ull hq[8][4];
    #pragma unroll
    for (int s = 0; s < 8; ++s)
      #pragma unroll
      for (int q = 0; q < 4; ++q)
        hq[s][q] = __hip_atomic_load(hb + s*16 + lk*4 + q,
                                     __ATOMIC_RELAXED, __HIP_MEMORY_SCOPE_AGENT);
    if (t) {
      for (;;) {
        bool ok = true;
        #pragma unroll
        for (int s = 0; s < 8; ++s)
          #pragma unroll
          for (int q = 0; q < 4; ++q) {
            u32 a = (u32)hq[s][q], b = (u32)(hq[s][q] >> 32);
            ok = ok && (a != 0u) && (b != 0u);
          }
        if (__all(ok)) break;
        __builtin_amdgcn_s_sleep(1);
        #pragma unroll
        for (int s = 0; s < 8; ++s)
          #pragma unroll
          for (int q = 0; q < 4; ++q)
            hq[s][q] = __hip_atomic_load(hb + s*16 + lk*4 + q,
                                         __ATOMIC_RELAXED, __HIP_MEMORY_SCOPE_AGENT);
      }
    }

    f32x4 acc[2];
    acc[0] = (f32x4){0.f,0.f,0.f,0.f};
    acc[1] = (f32x4){0.f,0.f,0.f,0.f};

    #pragma unroll
    for (int s = 0; s < 2; ++s) {
      float vv[8];
      if (s == 0) { vv[0]=xv0.x;vv[1]=xv0.y;vv[2]=xv0.z;vv[3]=xv0.w;vv[4]=xv1.x;vv[5]=xv1.y;vv[6]=xv1.z;vv[7]=xv1.w; }
      else        { vv[0]=xv2.x;vv[1]=xv2.y;vv[2]=xv2.z;vv[3]=xv2.w;vv[4]=xv3.x;vv[5]=xv3.y;vv[6]=xv3.z;vv[7]=xv3.w; }
      short8 ah, al2;
      #pragma unroll
      for (int j = 0; j < 8; ++j) {
        u16 h = f2bf(vv[j]);
        ah[j] = (short)h;
        al2[j] = (short)f2bf(vv[j] - bf2f(h));
      }
      #pragma unroll
      for (int c = 0; c < 2; ++c) {
        acc[c] = __builtin_amdgcn_mfma_f32_16x16x32_bf16(ah,  wpH[s][c], acc[c], 0,0,0);
        acc[c] = __builtin_amdgcn_mfma_f32_16x16x32_bf16(al2, wpH[s][c], acc[c], 0,0,0);
        acc[c] = __builtin_amdgcn_mfma_f32_16x16x32_bf16(ah,  wpL[s][c], acc[c], 0,0,0);
      }
    }
    #pragma unroll
    for (int s = 0; s < 8; ++s) {
      short8 ah, al2;
      #pragma unroll
      for (int q = 0; q < 4; ++q) {
        u32 w0 = (u32)hq[s][q], w1 = (u32)(hq[s][q] >> 32);
        ah[q*2]   = (short)(w0 >> 16); al2[q*2]   = (short)(w0 & 0xffff);
        ah[q*2+1] = (short)(w1 >> 16); al2[q*2+1] = (short)(w1 & 0xffff);
      }
      #pragma unroll
      for (int c = 0; c < 2; ++c) {
        acc[c] = __builtin_amdgcn_mfma_f32_16x16x32_bf16(ah,  whH[s][c], acc[c], 0,0,0);
        acc[c] = __builtin_amdgcn_mfma_f32_16x16x32_bf16(al2, whH[s][c], acc[c], 0,0,0);
        acc[c] = __builtin_amdgcn_mfma_f32_16x16x32_bf16(ah,  whL[s][c], acc[c], 0,0,0);
      }
    }

    const int p = t & 1;
    #pragma unroll
    for (int c = 0; c < 2; ++c)
      #pragma unroll
      for (int j = 0; j < 4; ++j)
        G[p][lk*4 + j][ug2*16 + lr][g0 + c] = acc[c][j];
    __syncthreads();

    #pragma unroll
    for (int pp = 0; pp < 2; ++pp) {
      int row = er0 + pp*8;
      float4 gq = *(const float4*)&G[p][row][ul][0];
      float gi = gq.x + bb[0], gf = gq.y + bb[1];
      float gg = gq.z + bb[2], go = gq.w + bb[3];
      float cn = sigm(gf)*cs[pp] + sigm(gi)*tanhf(gg);
      float hn = sigm(go)*tanhf(cn);
      cs[pp] = cn;
      as_(hz + (size_t)(t+1)*HSTR + (size_t)(rg*16 + row)*256 + bg*32 + ul,
          packhl(hn) | 1u);
    }
  }
}

// ---------------------------------------------------------------------------
// MLP layer-loop core, 512 thr = 8 waves (2 row-groups x 4 col-groups).
// act: [64][256] u32 packhl, chunk-swizzled. Leaves final activations in act.
// ---------------------------------------------------------------------------
static __device__ __forceinline__ void mlp_core(
    u32* act, const u16* wFL, const float* bs, const float* bl,
    int L, int nbs, bool lastRelu, int tid)
{
  const int l = tid & 63, w = tid >> 6;
  const int rg = w >> 2, cg = w & 3;
  const int lr = l & 15, lk = l >> 4;
  const int wrow = rg*32;
  f32x4 acc[2][4];
  for (int lyr = 0; lyr < L; ++lyr) {
    __syncthreads();
    const u16* wb = wFL + (size_t)lyr*131072;
    #pragma unroll
    for (int rt = 0; rt < 2; ++rt)
      #pragma unroll
      for (int ct = 0; ct < 4; ++ct) acc[rt][ct] = (f32x4){0.f,0.f,0.f,0.f};

    short8 bh[2][4], blo[2][4];
    #pragma unroll
    for (int ct = 0; ct < 4; ++ct) {
      const u16* bfp = wb + ((size_t)(cg*4 + ct))*512 + l*8;
      bh[0][ct]  = *(const short8*)bfp;
      blo[0][ct] = *(const short8*)(bfp + 65536);
    }
    #pragma unroll
    for (int s = 0; s < 8; ++s) {
      const int pb = s & 1, nb = pb ^ 1;
      if (s < 7) {
        #pragma unroll
        for (int ct = 0; ct < 4; ++ct) {
          const u16* bfp = wb + ((size_t)((s+1)*16 + cg*4 + ct))*512 + l*8;
          bh[nb][ct]  = *(const short8*)bfp;
          blo[nb][ct] = *(const short8*)(bfp + 65536);
        }
      }
      short8 ah[2], al2[2];
      #pragma unroll
      for (int rt = 0; rt < 2; ++rt) {
        int row = wrow + rt*16 + lr;
        int cc = s*8 + lk*2;
        const u32* base = act + row*256;
        uint4 d0 = *(const uint4*)(base + (((cc    ) ^ (row & 7)) << 2));
        uint4 d1 = *(const uint4*)(base + (((cc + 1) ^ (row & 7)) << 2));
        u32 q[8] = {d0.x,d0.y,d0.z,d0.w,d1.x,d1.y,d1.z,d1.w};
        #pragma unroll
        for (int j = 0; j < 8; ++j) {
          ah[rt][j]  = (short)(q[j] >> 16);
          al2[rt][j] = (short)(q[j] & 0xffff);
        }
      }
      #pragma unroll
      for (int ct = 0; ct < 4; ++ct)
        #pragma unroll
        for (int rt = 0; rt < 2; ++rt) {
          acc[rt][ct] = __builtin_amdgcn_mfma_f32_16x16x32_bf16(ah[rt],  bh[pb][ct],  acc[rt][ct], 0,0,0);
          acc[rt][ct] = __builtin_amdgcn_mfma_f32_16x16x32_bf16(al2[rt], bh[pb][ct],  acc[rt][ct], 0,0,0);
          acc[rt][ct] = __builtin_amdgcn_mfma_f32_16x16x32_bf16(ah[rt],  blo[pb][ct], acc[rt][ct], 0,0,0);
        }
    }
    const float* bptr = (lyr < nbs) ? (bs + lyr*256) : bl;
    const bool dorelu = (lyr < L-1) || lastRelu;
    #pragma unroll
    for (int ct = 0; ct < 4; ++ct) {
      float bv = bptr[cg*64 + ct*16 + lr];
      #pragma unroll
      for (int rt = 0; rt < 2; ++rt)
        #pragma unroll
        for (int g = 0; g < 4; ++g) {
          float xv = acc[rt][ct][g] + bv;
          acc[rt][ct][g] = dorelu ? fmaxf(xv, 0.f) : xv;
        }
    }
    __syncthreads();
    #pragma unroll
    for (int ct = 0; ct < 4; ++ct) {
      int n = cg*64 + ct*16 + lr;
      #pragma unroll
      for (int rt = 0; rt < 2; ++rt)
        #pragma unroll
        for (int g = 0; g < 4; ++g) {
          int row = wrow + rt*16 + lk*4 + g;
          act[row*256 + (((n >> 2) ^ (row & 7)) << 2) + (n & 3)] = packhl(acc[rt][ct][g]);
        }
    }
  }
  __syncthreads();
}

// ---------------------------------------------------------------------------
// MEGA decode kernel, 512 thr: whs-MLP + 8 x {u -> v -> attn -> cell+outproj}.
// 256 blocks, 64KB LDS, co-resident. Sync identical to r10 (proven).
// ---------------------------------------------------------------------------
__global__ __launch_bounds__(512,1) void k_dec_all(
    const u32* __restrict__ henc, const u16* __restrict__ mlpFL,
    const float* __restrict__ wbs, const float* __restrict__ wbl,
    const float* __restrict__ ubs, const float* __restrict__ ubl,
    const float* __restrict__ vbs, const float* __restrict__ vWl,
    const float* __restrict__ vbl,
    const float* __restrict__ dWt, const float* __restrict__ dbih,
    const float* __restrict__ dbhh,
    const float* __restrict__ oW, const float* __restrict__ ob,
    u32* __restrict__ whsP, u32* __restrict__ usb, u32* __restrict__ usflag,
    u32* __restrict__ eS, u32* __restrict__ ctxS, u32* __restrict__ sS,
    float* __restrict__ outc)
{
  extern __shared__ u32 act[];            // 64KB
  __shared__ float red[8], red2[8];
  const int bid = blockIdx.x, tid = threadIdx.x;
  const u16* wFLw = mlpFL;
  const u16* wFLu = mlpFL + 4*131072;
  const u16* wFLv = mlpFL + 8*131072;
  float sprev[4] = {0.f, 0.f, 0.f, 0.f};

  // ======== whs stage: 4 block-local tiles ========
  for (int k = 0; k < 4; ++k) {
    long m0t = (long)(bid + 256*k) * 64;
    __syncthreads();
    for (int i = tid; i < 4096; i += 512) {
      int row = i >> 6, c16 = i & 63;
      long m = m0t + row;
      uint4 pk = *(const uint4*)(henc + HSTR + m*256 + c16*4);
      *((uint4*)(act + row*256 + ((c16 ^ (row & 7)) << 2))) = pk;
    }
    mlp_core(act, wFLw, wbs, wbl, 4, 3, false, tid);
    for (int i = tid; i < 4096; i += 512) {
      int row = i >> 6, c16 = i & 63;
      long m = m0t + row;
      uint4 pk = *((const uint4*)(act + row*256 + ((c16 ^ (row & 7)) << 2)));
      *(uint4*)(whsP + m*256 + c16*4) = pk;
    }
  }

  // ======== decode steps ========
  for (int s = 0; s < OL_; ++s) {
    // ---- u-stage (blocks 0,1)
    if (bid < 2) {
      long m0t = (long)bid * 64;
      __syncthreads();
      for (int i = tid; i < 4096; i += 512) {
        int row = i >> 6, c16 = i & 63;
        const u32* sp = sS + (size_t)s*32768 + (m0t + row)*256 + c16*4;
        u32 w0 = al(sp), w1 = al(sp+1), w2 = al(sp+2), w3 = al(sp+3);
        if (s) {
          while (!(w0 && w1 && w2 && w3)) {
            __builtin_amdgcn_s_sleep(1);
            w0 = al(sp); w1 = al(sp+1); w2 = al(sp+2); w3 = al(sp+3);
          }
        }
        uint4 pk = { packhl(__uint_as_float(w0)), packhl(__uint_as_float(w1)),
                     packhl(__uint_as_float(w2)), packhl(__uint_as_float(w3)) };
        *((uint4*)(act + row*256 + ((c16 ^ (row & 7)) << 2))) = pk;
      }
      mlp_core(act, wFLu, ubs, ubl, 4, 3, false, tid);
      for (int i = tid; i < 4096; i += 512) {
        int row = i >> 6, c16 = i & 63;
        uint4 pk = *((const uint4*)(act + row*256 + ((c16 ^ (row & 7)) << 2)));
        *(uint4*)(usb + (size_t)s*32768 + (m0t + row)*256 + c16*4) = pk;
      }
      __syncthreads();                    // drain us stores
      if (tid == 0)
        __hip_atomic_store(usflag + s*2 + bid, 1u,
                           __ATOMIC_RELEASE, __HIP_MEMORY_SCOPE_AGENT);
    }

    // ---- wait us ready (one wave polls, block follows)
    {
      if (tid < 64) {
        const u32* f0 = usflag + s*2;
        for (;;) {
          u32 a0 = al(f0), a1 = al(f0 + 1);
          if (a0 & a1) break;
          __builtin_amdgcn_s_sleep(2);
        }
      }
      __syncthreads();
      __builtin_amdgcn_fence(__ATOMIC_ACQUIRE, "agent");
    }

    // ---- v-stage: 4 tiles
    for (int k = 0; k < 4; ++k) {
      long m0t = (long)(bid + 256*k) * 64;
      __syncthreads();
      for (int i = tid; i < 4096; i += 512) {
        int row = i >> 6, c16 = i & 63;
        long m = m0t + row;
        uint4 pw = *(const uint4*)(whsP + m*256 + c16*4);
        uint4 uw = *(const uint4*)(usb + (size_t)s*32768 + (m & 127)*256 + c16*4);
        uint4 pk;
        pk.x = packhl(tanhf(unpackhl(pw.x) + unpackhl(uw.x)));
        pk.y = packhl(tanhf(unpackhl(pw.y) + unpackhl(uw.y)));
        pk.z = packhl(tanhf(unpackhl(pw.z) + unpackhl(uw.z)));
        pk.w = packhl(tanhf(unpackhl(pw.w) + unpackhl(uw.w)));
        *((uint4*)(act + row*256 + ((c16 ^ (row & 7)) << 2))) = pk;
      }
      mlp_core(act, wFLv, vbs, vbs, 7, 7, true, tid);
      // e-dot: 8 threads per row (32 cols each)
      {
        int r2 = tid >> 3, q = tid & 7;
        float p = 0.f;
        #pragma unroll 8
        for (int j = 0; j < 32; ++j) {
          int n = q*32 + j;
          u32 w = act[r2*256 + (((n >> 2) ^ (r2 & 7)) << 2) + (n & 3)];
          p += unpackhl(w) * vWl[n];
        }
        p += __shfl_xor(p, 1, 64);
        p += __shfl_xor(p, 2, 64);
        p += __shfl_xor(p, 4, 64);
        if (q == 0)
          as_(eS + (size_t)s*65536 + m0t + r2, __float_as_uint(p + vbl[0]) | 1u);
      }
    }

    // ---- attn (blocks 64..191): row b = bid-64
    if (bid >= 64 && bid < 192) {
      int b = bid - 64;
      __syncthreads();                    // reclaim act
      float* asx = (float*)act;           // [512] weights + [512] partials
      const u32* ep0 = eS + (size_t)s*65536 + b;
      u32 w0;
      for (;;) {
        w0 = al(ep0 + (size_t)tid*128);
        if (w0) break;
        __builtin_amdgcn_s_sleep(1);
      }
      float v0 = __uint_as_float(w0);
      const int lane = tid & 63, wv = tid >> 6;
      float m = v0;
      #pragma unroll
      for (int o = 32; o; o >>= 1) m = fmaxf(m, __shfl_xor(m, o, 64));
      if (!lane) red[wv] = m;
      __syncthreads();
      m = fmaxf(fmaxf(fmaxf(red[0], red[1]), fmaxf(red[2], red[3])),
                fmaxf(fmaxf(red[4], red[5]), fmaxf(red[6], red[7])));
      float x0 = expf(v0 - m);
      float sm = x0;
      #pragma unroll
      for (int o = 32; o; o >>= 1) sm += __shfl_xor(sm, o, 64);
      if (!lane) red2[wv] = sm;
      __syncthreads();
      float inv = 1.f / (red2[0] + red2[1] + red2[2] + red2[3]
                       + red2[4] + red2[5] + red2[6] + red2[7]);
      asx[tid] = x0 * inv;
      __syncthreads();
      // ctx: 2 threads per unit, each sums half the t-range
      int unit = tid & 255, half = tid >> 8;
      float accv = 0.f;
      const u32* hp = henc + HSTR + (size_t)b*256 + unit;
      #pragma unroll 8
      for (int t = half*256; t < half*256 + 256; ++t)
        accv += asx[t] * unpackhl(hp[(size_t)t*HSTR]);
      float* part = asx + 512;
      part[tid] = accv;
      __syncthreads();
      if (half == 0)
        as_(ctxS + (size_t)s*32768 + b*256 + unit,
            __float_as_uint(accv + part[256 + unit]) | 1u);
    }

    // ---- cell + outproj (blocks 224..255): rows 4c..4c+3
    if (bid >= 224) {
      int c = bid - 224, b0r = c*4;
      __syncthreads();                    // reclaim act
      float* xt = (float*)act;            // [4][520]
      const int u = tid & 255, kh = tid >> 8;
      if (kh == 0) {
        const u32* cp = ctxS + (size_t)s*32768 + (size_t)b0r*256 + u;
        u32 w0, w1, w2, w3;
        for (;;) {
          w0 = al(cp); w1 = al(cp + 256); w2 = al(cp + 512); w3 = al(cp + 768);
          if (w0 && w1 && w2 && w3) break;
          __builtin_amdgcn_s_sleep(1);
        }
        xt[0*520 + u] = __uint_as_float(w0);
        xt[1*520 + u] = __uint_as_float(w1);
        xt[2*520 + u] = __uint_as_float(w2);
        xt[3*520 + u] = __uint_as_float(w3);
        #pragma unroll
        for (int bb = 0; bb < 4; ++bb) xt[bb*520 + 256 + u] = sprev[bb];
      }
      __syncthreads();
      float ai[4], ag[4], ao[4];
      #pragma unroll
      for (int bb = 0; bb < 4; ++bb) { ai[bb]=0.f; ag[bb]=0.f; ao[bb]=0.f; }
      #pragma unroll 4
      for (int k = kh*256; k < kh*256 + 256; ++k) {
        float wi = dWt[k*768 + u];
        float wg = dWt[k*768 + 256 + u];
        float wo = dWt[k*768 + 512 + u];
        #pragma unroll
        for (int bb = 0; bb < 4; ++bb) {
          float xv = xt[bb*520 + k];
          ai[bb] += xv*wi; ag[bb] += xv*wg; ao[bb] += xv*wo;
        }
      }
      float* pr = xt + 4*520;             // partials [3][4][256]
      if (kh) {
        #pragma unroll
        for (int bb = 0; bb < 4; ++bb) {
          pr[(0*4 + bb)*256 + u] = ai[bb];
          pr[(1*4 + bb)*256 + u] = ag[bb];
          pr[(2*4 + bb)*256 + u] = ao[bb];
        }
      }
      __syncthreads();
      float* sn = pr + 3*4*256;           // [4][256]
      if (!kh) {
        float bi = dbih[u]       + dbhh[u];
        float bg = dbih[512 + u] + dbhh[512 + u];
        float bo = dbih[768 + u] + dbhh[768 + u];
        #pragma unroll
        for (int bb = 0; bb < 4; ++bb) {
          float a1 = ai[bb] + pr[(0*4 + bb)*256 + u];
          float g1 = ag[bb] + pr[(1*4 + bb)*256 + u];
          float o1 = ao[bb] + pr[(2*4 + bb)*256 + u];
          float cn = sigm(a1 + bi) * tanhf(g1 + bg);
          float hn = sigm(o1 + bo) * tanhf(cn);
          as_(sS + (size_t)(s+1)*32768 + (size_t)(b0r + bb)*256 + u,
              __float_as_uint(hn) | 1u);
          sprev[bb] = hn;
          sn[bb*256 + u] = hn;
        }
      }
      __syncthreads();
      if (tid < 256) {
        int d = tid & 63, rr = tid >> 6;
        float a2 = ob[d];
        #pragma unroll 4
        for (int k = 0; k < 256; ++k) a2 += sn[rr*256 + k] * oW[k*64 + d];
        outc[((size_t)(b0r + rr)*OL_ + s)*64 + d] = a2;
      }
    }
  }
  (void)wFLw;
}

// ---------------------------------------------------------------------------
extern "C" void kernel_launch(void* const* d_in, const int* in_sizes, int n_in,
                              void* d_out, int out_size, void* d_ws, size_t ws_size,
                              hipStream_t stream)
{
  (void)in_sizes; (void)n_in;
  const float* x    = (const float*)d_in[0];
  const float* inW  = (const float*)d_in[1];
  const float* inb  = (const float*)d_in[2];
  const float* eWih = (const float*)d_in[3];
  const float* eWhh = (const float*)d_in[4];
  const float* ebih = (const float*)d_in[5];
  const float* ebhh = (const float*)d_in[6];
  const float* dWih = (const float*)d_in[7];
  const float* dbih = (const float*)d_in[9];
  const float* dbhh = (const float*)d_in[10];
  const float* wWs  = (const float*)d_in[11];
  const float* wbs  = (const float*)d_in[12];
  const float* wWl  = (const float*)d_in[13];
  const float* wbl  = (const float*)d_in[14];
  const float* uWs  = (const float*)d_in[15];
  const float* ubs  = (const float*)d_in[16];
  const float* uWl  = (const float*)d_in[17];
  const float* ubl  = (const float*)d_in[18];
  const float* vWs  = (const float*)d_in[19];
  const float* vbs  = (const float*)d_in[20];
  const float* vWl  = (const float*)d_in[21];
  const float* vbl  = (const float*)d_in[22];
  const float* oW   = (const float*)d_in[23];
  const float* ob   = (const float*)d_in[24];
  float* out = (float*)d_out;

  hipFuncSetAttribute((const void*)k_dec_all, hipFuncAttributeMaxDynamicSharedMemorySize, 65536);

  const size_t hsz = (size_t)(T_+1) * HSTR;     // u32 per chunk
  const size_t avail = ws_size / 4;
  auto needf = [&](int nc) -> size_t {
    return (size_t)nc*hsz + 16777216ull /*whsP*/ + 1343552ull /*scratch*/
         + 1770496ull /*preps*/ + 4096;
  };
  int NC = (needf(2) <= avail) ? 2 : 1;
  if (needf(NC) > avail) { hipMemsetAsync(d_out, 0, (size_t)out_size*4, stream); return; }

  float* wsf = (float*)d_ws;
  size_t o = 0;
  u32* henc = (u32*)(wsf + o);  o += (size_t)NC*hsz;
  u32* whsP = (u32*)(wsf + o);  o += 16777216;
  u32* usb  = (u32*)(wsf + o);  o += 262144;       // scratch block start
  u32* usflag = (u32*)(wsf + o); o += 64;
  u32* eS   = (u32*)(wsf + o);  o += 524288;
  u32* ctxS = (u32*)(wsf + o);  o += 262144;
  u32* sS   = (u32*)(wsf + o);  o += 294912;       // scratch block end
  float* WpT = wsf + o;  o += 65536;
  float* bp  = wsf + o;  o += 1024;
  float* dWt = wsf + o;  o += 393216;
  u16* whhFL = (u16*)(wsf + o);  o += 262144;
  u16* wpFL  = (u16*)(wsf + o);  o += 65536;
  u16* mlpFL = (u16*)(wsf + o);                    // 983040 units

  const size_t scratchBytes = (262144ull + 64 + 524288 + 262144 + 294912) * 4;

  // ---- weight preps (chunk-invariant)
  k_wpt<<<256, 256, 0, stream>>>(inW, eWih, WpT);
  k_bp <<<4,   256, 0, stream>>>(inb, eWih, ebih, ebhh, bp);
  k_dwt<<<1536,256, 0, stream>>>(dWih, dWt);
  k_whhfl<<<1024,256,0,stream>>>(eWhh, whhFL);
  k_wpfl <<<256, 256,0,stream>>>(WpT, wpFL);
  k_wall <<<dim3(256,15), 256, 0, stream>>>(wWs, wWl, uWs, uWl, vWs, mlpFL);

  for (int c0 = 0; c0 < B_; c0 += CBv*NC) {
    hipMemsetAsync(henc, 0, (size_t)NC*hsz*4, stream);   // data-as-flag: clean

    // concurrent chunk encoders
    k_enc<<<dim3(CBv/16, 8, NC), 256, 0, stream>>>(
        x + (size_t)c0*T_*DIN_, whhFL, wpFL, bp, henc);

    for (int z = 0; z < NC; ++z) {
      hipMemsetAsync(usb, 0, scratchBytes, stream);      // step-flags clean
      k_dec_all<<<256, 512, 65536, stream>>>(
          henc + (size_t)z*hsz, mlpFL,
          wbs, wbl, ubs, ubl, vbs, vWl, vbl,
          dWt, dbih, dbhh, oW, ob,
          whsP, usb, usflag, eS, ctxS, sS,
          out + (size_t)(c0 + z*CBv)*OL_*DOUT_);
    }
  }
}